// Round 4
// baseline (592.241 us; speedup 1.0000x reference)
//
#include <hip/hip_runtime.h>
#include <math.h>

#define TPB 256
typedef unsigned short ushort_t;
typedef unsigned int uint_t;
typedef __attribute__((ext_vector_type(8))) short bf16x8;
typedef __attribute__((ext_vector_type(4))) float f32x4;

__device__ __forceinline__ float bf2f(ushort_t h) {
    return __uint_as_float(((uint_t)h) << 16);
}
__device__ __forceinline__ ushort_t f2bf(float f) {
    uint_t u = __float_as_uint(f);
    u += 0x7fff + ((u >> 16) & 1);
    return (ushort_t)(u >> 16);
}
__device__ __forceinline__ uint_t pack2(float x, float y) {
    return (uint_t)f2bf(x) | ((uint_t)f2bf(y) << 16);
}

#define SWZ_A 32768
#define SWZ_B 24576
#define SWZ_C 12288
#define SWZ_D 12288

// ==================== fused preamble: rank (atomics) || weight swizzle || x->bf16 ====================
// The rank part is bound by device-scope atomic throughput (~24 G/s, 67us) with VALU/HBM idle;
// the swz+cvt work (BW-bound, ~14us) rides along for free.
__global__ __launch_bounds__(256)
void pre1(const int* __restrict__ col, int* __restrict__ cnt, unsigned short* __restrict__ pos,
          int E, int nEb,
          const float* __restrict__ w1_init, const float* __restrict__ w1,
          const float* __restrict__ w1_root, const float* __restrict__ w2_init,
          const float* __restrict__ w2, const float* __restrict__ w2_root,
          short* __restrict__ swzdst, int nSb,
          const float4* __restrict__ x, uint2* __restrict__ xh, int n4) {
    int b = blockIdx.x;
    if (b < nEb) {
        int e = b * 256 + threadIdx.x;
        if (e < E) pos[e] = (unsigned short)atomicAdd(&cnt[col[e]], 1);
        return;
    }
    if (b < nEb + nSb) {
        int idx = (b - nEb) * 256 + threadIdx.x;
        int region, base, CH, CT;
        if (idx < SWZ_A)                          { region = 0; base = 0; CH = 4; CT = 8; }
        else if (idx < SWZ_A + SWZ_B)             { region = 1; base = SWZ_A; CH = 6; CT = 4; }
        else if (idx < SWZ_A + SWZ_B + SWZ_C)     { region = 2; base = SWZ_A + SWZ_B; CH = 2; CT = 6; }
        else if (idx < SWZ_A + SWZ_B + SWZ_C + SWZ_D)
                                                  { region = 3; base = SWZ_A + SWZ_B + SWZ_C; CH = 4; CT = 3; }
        else return;
        int r = idx - base;
        int j = r & 7, ln = (r >> 3) & 63;
        int rest = r >> 9;
        int ct = rest % CT, c = (rest / CT) % CH, k = rest / (CT * CH);
        int colm = ct * 16 + (ln & 15);
        int kl = (ln >> 4) * 8 + j;
        float v = 0.0f;
        if (region == 0) {              // L1-t0: x(128) -> [init(64) | root_t0(64)]
            int kk = c * 32 + kl;
            if (colm < 64)       v = w1_init[((size_t)k * 128 + kk) * 64 + colm];
            else                 v = w1_root[((size_t)k * 128 + kk) * 64 + (colm - 64)];
        } else if (region == 1) {       // L1-t1: c<2: agg(64)@w1 ; c>=2: x(128)@root_t1
            if (c < 2) { int kk = c * 32 + kl;        v = w1[((size_t)k * 64 + kk) * 64 + colm]; }
            else       { int kk = (c - 2) * 32 + kl;  v = w1_root[((size_t)(2 + k) * 128 + kk) * 64 + colm]; }
        } else if (region == 2) {       // L2-t0: h(64) -> [init(41,pad48) | root_t0(41,pad48)]
            int kk = c * 32 + kl;
            if (colm < 48) { if (colm < 41)           v = w2_init[((size_t)k * 64 + kk) * 41 + colm]; }
            else           { int c2 = colm - 48; if (c2 < 41) v = w2_root[((size_t)k * 64 + kk) * 41 + c2]; }
        } else {                        // L2-t1: c<2: agg(48,rows41)@w2 ; c>=2: h(64)@root_t1
            if (c < 2) { int kk = c * 32 + kl;       if (kk < 41 && colm < 41) v = w2[((size_t)k * 41 + kk) * 41 + colm]; }
            else       { int kk = (c - 2) * 32 + kl; if (colm < 41)            v = w2_root[((size_t)(2 + k) * 64 + kk) * 41 + colm]; }
        }
        swzdst[(size_t)base + r] = (short)f2bf(v);
        return;
    }
    int i = (b - nEb - nSb) * 256 + threadIdx.x;
    if (i < n4) {
        float4 v = x[i];
        xh[i] = make_uint2(pack2(v.x, v.y), pack2(v.z, v.w));
    }
}

// ==================== scan chain (unchanged) ====================
__global__ void scan_block(const int* __restrict__ cnt, int* __restrict__ incl,
                           int* __restrict__ bsum, int N) {
    __shared__ int s[TPB];
    int i = blockIdx.x * TPB + threadIdx.x;
    s[threadIdx.x] = (i < N) ? ((cnt[i] + 3) & ~3) : 0;   // padded counts
    __syncthreads();
    for (int d = 1; d < TPB; d <<= 1) {
        int t = (threadIdx.x >= d) ? s[threadIdx.x - d] : 0;
        __syncthreads();
        s[threadIdx.x] += t;
        __syncthreads();
    }
    if (i < N) incl[i] = s[threadIdx.x];
    if (threadIdx.x == TPB - 1) bsum[blockIdx.x] = s[TPB - 1];
}

__global__ void scan_bsums(int* __restrict__ bsum, int nb) {
    __shared__ int s[512];
    int t = threadIdx.x;
    int v = (t < nb) ? bsum[t] : 0;
    s[t] = v;
    __syncthreads();
    for (int d = 1; d < 512; d <<= 1) {
        int u = (t >= d) ? s[t - d] : 0;
        __syncthreads();
        s[t] += u;
        __syncthreads();
    }
    if (t < nb) bsum[t] = s[t] - v;
}

__global__ void finalize_csr(const int* __restrict__ incl, const int* __restrict__ bsum,
                             const int* __restrict__ cnt, int* __restrict__ rowstart,
                             float* __restrict__ dinv, int N) {
    int i = blockIdx.x * TPB + threadIdx.x;
    if (i < N) {
        rowstart[i + 1] = incl[i] + bsum[blockIdx.x];
        int d = cnt[i];
        dinv[i] = (d > 0) ? rsqrtf((float)d) : 0.0f;
    }
    if (i == 0) rowstart[0] = 0;
}

// ==================== t0 GEMM, optionally fused with CSR fill+pad ====================
// When fbBlocks > 0, blocks are chunk-interleaved 2 gemm : 6 fill so the
// latency-bound scattered CSR fill co-resides with the MFMA-bound gemm.
template<int CT, int CTA, int CH>
__global__ __launch_bounds__(256, 4)
void gemm_t0_f(const ushort_t* __restrict__ s2, int s2s, const short* __restrict__ fragbuf,
               const float* __restrict__ biasB, const float* __restrict__ dinv,
               int FB, int N, uint_t* __restrict__ pre, uint_t* __restrict__ outH,
               int GB, int fbBlocks,
               const int* __restrict__ rowv, const int* __restrict__ colv,
               const int* __restrict__ rowstart, const unsigned short* __restrict__ pos,
               const int* __restrict__ cnt, int* __restrict__ srcidx, int E) {
    constexpr int PP = (CT - CTA) * 8;
    constexpr int PA = CTA * 8;
    __shared__ short lds_b[CH * CT * 512];

    int gid;
    {
        int b = blockIdx.x;
        if (fbBlocks == 0) {
            gid = b;
        } else {
            int r = b & 7, c = b >> 3;
            if (r < 2) {
                gid = c * 2 + r;
            } else {
                int fid = c * 6 + (r - 2);
                if (fid < fbBlocks) {
                    int id = fid * 256 + (int)threadIdx.x;
                    if (id < E) {
                        srcidx[rowstart[colv[id]] + (int)pos[id]] = rowv[id];
                    } else if (id - E < N) {
                        int i = id - E;
                        int bg = rowstart[i] + cnt[i], en = rowstart[i + 1];
                        for (int e = bg; e < en; ++e) srcidx[e] = N;  // sentinel
                    }
                }
                return;
            }
        }
    }
    if (gid >= GB * 2) return;
    const int k = gid / GB;
    const int n0 = (gid - k * GB) * 128;
    const int t = threadIdx.x;
    const int w = t >> 6, lane = t & 63, quad = lane >> 4, lr = lane & 15;
    const short* fb = fragbuf + (size_t)k * CH * CT * 512;

    int r0 = n0 + w * 32 + lr;
    int m0 = r0 < N ? r0 : N - 1;
    int m1 = (r0 + 16) < N ? (r0 + 16) : N - 1;

    // hoisted A loads: all in flight before staging
    bf16x8 a0v[CH], a1v[CH];
#pragma unroll
    for (int c = 0; c < CH; ++c) {
        int off = c * 32 + quad * 8;
        a0v[c] = *(const bf16x8*)&s2[(size_t)m0 * s2s + off];
        a1v[c] = *(const bf16x8*)&s2[(size_t)m1 * s2s + off];
    }

    {
        constexpr int CHUNKS = CH * CT * 64;   // bf16x8 chunks
#pragma unroll
        for (int i = 0; i < (CHUNKS + 255) / 256; ++i) {
            int idx = i * 256 + t;
            if (CHUNKS % 256 == 0 || idx < CHUNKS)
                *(bf16x8*)&lds_b[idx * 8] = *(const bf16x8*)&fb[(size_t)idx * 8];
        }
    }
    __syncthreads();

    f32x4 acc[2][CT];
#pragma unroll
    for (int rt = 0; rt < 2; ++rt)
#pragma unroll
        for (int ct = 0; ct < CT; ++ct) acc[rt][ct] = (f32x4){0.f, 0.f, 0.f, 0.f};

#pragma unroll
    for (int c = 0; c < CH; ++c) {
#pragma unroll
        for (int ct = 0; ct < CT; ++ct) {
            bf16x8 bfr = *(const bf16x8*)&lds_b[((size_t)c * CT + ct) * 512 + lane * 8];
            acc[0][ct] = __builtin_amdgcn_mfma_f32_16x16x32_bf16(a0v[c], bfr, acc[0][ct], 0, 0, 0);
            acc[1][ct] = __builtin_amdgcn_mfma_f32_16x16x32_bf16(a1v[c], bfr, acc[1][ct], 0, 0, 0);
        }
    }

#pragma unroll
    for (int rt = 0; rt < 2; ++rt) {
#pragma unroll
        for (int i = 0; i < 4; ++i) {
            int n = n0 + w * 32 + rt * 16 + quad * 4 + i;
            if (n >= N) continue;
            float dnv = dinv[n];
#pragma unroll
            for (int ct = 0; ct < CT; ++ct) {
                int col = ct * 16 + lr;
                float v = acc[rt][ct][i];
                if (ct < CTA) {
                    v *= dnv;                       // pre-scale msg by dinv[src]
                } else {
                    int c2 = col - CTA * 16;
                    if (c2 < FB) v += biasB[(size_t)k * FB + c2];
                }
                float vn = __shfl_xor(v, 1);
                uint_t p = pack2(v, vn);
                uint_t p2 = __shfl_xor(p, 2);
                if (!(lr & 3)) {
                    if (ct < CTA) {
                        *(uint2*)&outH[((size_t)n * 2 + k) * PA + (col >> 1)] = make_uint2(p, p2);
                    } else {
                        int c2 = col - CTA * 16;
                        *(uint2*)&pre[((size_t)n * 2 + k) * PP + (c2 >> 1)] = make_uint2(p, p2);
                    }
                }
            }
        }
    }
}

// ==================== t1 GEMM layer1: relu+mean -> hh bf16 ====================
__global__ __launch_bounds__(256, 3)
void gemm_t1_l1(const ushort_t* __restrict__ s1, const ushort_t* __restrict__ xh,
                const short* __restrict__ fragbuf, const float* __restrict__ bias,
                int N, uint_t* __restrict__ hhU) {
    constexpr int CT = 4, CH = 6;
    const int n0 = blockIdx.x * 128;
    const int t = threadIdx.x;
    const int w = t >> 6, lane = t & 63, quad = lane >> 4, lr = lane & 15;

    int r0 = n0 + w * 32 + lr;
    int m0 = r0 < N ? r0 : N - 1;
    int m1 = (r0 + 16) < N ? (r0 + 16) : N - 1;

    // hoisted A loads
    bf16x8 s0a[2][2], s1a[2][2];   // [c][k]
    bf16x8 x0a[4], x1a[4];
#pragma unroll
    for (int c = 0; c < 2; ++c) {
        int off = c * 32 + quad * 8;
#pragma unroll
        for (int kk = 0; kk < 2; ++kk) {
            s0a[c][kk] = *(const bf16x8*)&s1[((size_t)m0 * 2 + kk) * 64 + off];
            s1a[c][kk] = *(const bf16x8*)&s1[((size_t)m1 * 2 + kk) * 64 + off];
        }
    }
#pragma unroll
    for (int c = 0; c < 4; ++c) {
        int off = c * 32 + quad * 8;
        x0a[c] = *(const bf16x8*)&xh[(size_t)m0 * 128 + off];
        x1a[c] = *(const bf16x8*)&xh[(size_t)m1 * 128 + off];
    }

    __shared__ short lds_b[2 * CH * CT * 512];   // 48 KB, both k
    {
        constexpr int CHUNKS = 2 * CH * CT * 64;
#pragma unroll
        for (int i = 0; i < CHUNKS / 256; ++i) {
            int idx = i * 256 + t;
            *(bf16x8*)&lds_b[idx * 8] = *(const bf16x8*)&fragbuf[(size_t)idx * 8];
        }
    }
    __syncthreads();

    f32x4 acc[2][2][CT];
#pragma unroll
    for (int k = 0; k < 2; ++k)
#pragma unroll
        for (int rt = 0; rt < 2; ++rt)
#pragma unroll
            for (int ct = 0; ct < CT; ++ct) acc[k][rt][ct] = (f32x4){0.f, 0.f, 0.f, 0.f};

#pragma unroll
    for (int c = 0; c < CH; ++c) {
#pragma unroll
        for (int k = 0; k < 2; ++k) {
            bf16x8 a0 = (c < 2) ? s0a[c][k] : x0a[c - 2];
            bf16x8 a1 = (c < 2) ? s1a[c][k] : x1a[c - 2];
#pragma unroll
            for (int ct = 0; ct < CT; ++ct) {
                bf16x8 b = *(const bf16x8*)&lds_b[(((size_t)k * CH + c) * CT + ct) * 512 + lane * 8];
                acc[k][0][ct] = __builtin_amdgcn_mfma_f32_16x16x32_bf16(a0, b, acc[k][0][ct], 0, 0, 0);
                acc[k][1][ct] = __builtin_amdgcn_mfma_f32_16x16x32_bf16(a1, b, acc[k][1][ct], 0, 0, 0);
            }
        }
    }

#pragma unroll
    for (int rt = 0; rt < 2; ++rt) {
#pragma unroll
        for (int i = 0; i < 4; ++i) {
            int n = n0 + w * 32 + rt * 16 + quad * 4 + i;
            if (n >= N) continue;
#pragma unroll
            for (int ct = 0; ct < CT; ++ct) {
                int col = ct * 16 + lr;
                float v0 = fmaxf(acc[0][rt][ct][i] + bias[col], 0.0f);
                float v1 = fmaxf(acc[1][rt][ct][i] + bias[64 + col], 0.0f);
                float m = 0.5f * (v0 + v1);
                float mn = __shfl_xor(m, 1);
                uint_t p = pack2(m, mn);
                uint_t p2 = __shfl_xor(p, 2);
                if (!(lr & 3)) *(uint2*)&hhU[(size_t)n * 32 + (col >> 1)] = make_uint2(p, p2);
            }
        }
    }
}

// ===== t1 GEMM layer2: relu+mean+log_softmax -> d_out f32 =====
__global__ __launch_bounds__(256, 3)
void gemm_t1_l2(const ushort_t* __restrict__ s1, const ushort_t* __restrict__ hh,
                const short* __restrict__ fragbuf, const float* __restrict__ bias,
                int N, float* __restrict__ out) {
    constexpr int CT = 3, CH = 4;
    const int n0 = blockIdx.x * 128;
    const int t = threadIdx.x;
    const int w = t >> 6, lane = t & 63, quad = lane >> 4, lr = lane & 15;

    int r0 = n0 + w * 32 + lr;
    int m0 = r0 < N ? r0 : N - 1;
    int m1 = (r0 + 16) < N ? (r0 + 16) : N - 1;

    bf16x8 s0a[2][2], s1a[2][2];   // [c][k]
    bf16x8 h0a[2], h1a[2];
#pragma unroll
    for (int c = 0; c < 2; ++c) {
        int off = c * 32 + quad * 8;
#pragma unroll
        for (int kk = 0; kk < 2; ++kk) {
            s0a[c][kk] = *(const bf16x8*)&s1[((size_t)m0 * 2 + kk) * 48 + off];
            s1a[c][kk] = *(const bf16x8*)&s1[((size_t)m1 * 2 + kk) * 48 + off];
        }
    }
#pragma unroll
    for (int c = 0; c < 2; ++c) {
        int off = c * 32 + quad * 8;
        h0a[c] = *(const bf16x8*)&hh[(size_t)m0 * 64 + off];
        h1a[c] = *(const bf16x8*)&hh[(size_t)m1 * 64 + off];
    }

    __shared__ short lds_b[2 * CH * CT * 512];   // 24 KB, both k
    {
        constexpr int CHUNKS = 2 * CH * CT * 64;
#pragma unroll
        for (int i = 0; i < CHUNKS / 256; ++i) {
            int idx = i * 256 + t;
            *(bf16x8*)&lds_b[idx * 8] = *(const bf16x8*)&fragbuf[(size_t)idx * 8];
        }
    }
    __syncthreads();

    f32x4 acc[2][2][CT];
#pragma unroll
    for (int k = 0; k < 2; ++k)
#pragma unroll
        for (int rt = 0; rt < 2; ++rt)
#pragma unroll
            for (int ct = 0; ct < CT; ++ct) acc[k][rt][ct] = (f32x4){0.f, 0.f, 0.f, 0.f};

#pragma unroll
    for (int c = 0; c < CH; ++c) {
#pragma unroll
        for (int k = 0; k < 2; ++k) {
            bf16x8 a0 = (c < 2) ? s0a[c][k] : h0a[c - 2];
            bf16x8 a1 = (c < 2) ? s1a[c][k] : h1a[c - 2];
#pragma unroll
            for (int ct = 0; ct < CT; ++ct) {
                bf16x8 b = *(const bf16x8*)&lds_b[(((size_t)k * CH + c) * CT + ct) * 512 + lane * 8];
                acc[k][0][ct] = __builtin_amdgcn_mfma_f32_16x16x32_bf16(a0, b, acc[k][0][ct], 0, 0, 0);
                acc[k][1][ct] = __builtin_amdgcn_mfma_f32_16x16x32_bf16(a1, b, acc[k][1][ct], 0, 0, 0);
            }
        }
    }

#pragma unroll
    for (int rt = 0; rt < 2; ++rt) {
#pragma unroll
        for (int i = 0; i < 4; ++i) {
            int n = n0 + w * 32 + rt * 16 + quad * 4 + i;
            float m[CT];
            float mx = -1e30f;
#pragma unroll
            for (int ct = 0; ct < CT; ++ct) {
                int col = ct * 16 + lr;
                float b0 = (col < 41) ? bias[col] : 0.0f;
                float b1v = (col < 41) ? bias[41 + col] : 0.0f;
                float v0 = fmaxf(acc[0][rt][ct][i] + b0, 0.0f);
                float v1 = fmaxf(acc[1][rt][ct][i] + b1v, 0.0f);
                m[ct] = 0.5f * (v0 + v1);
                if (col < 41) mx = fmaxf(mx, m[ct]);
            }
#pragma unroll
            for (int msk = 1; msk < 16; msk <<= 1) mx = fmaxf(mx, __shfl_xor(mx, msk));
            float s = 0.0f;
#pragma unroll
            for (int ct = 0; ct < CT; ++ct) {
                int col = ct * 16 + lr;
                if (col < 41) s += __expf(m[ct] - mx);
            }
#pragma unroll
            for (int msk = 1; msk < 16; msk <<= 1) s += __shfl_xor(s, msk);
            float ls = __logf(s);
            if (n < N) {
#pragma unroll
                for (int ct = 0; ct < CT; ++ct) {
                    int col = ct * 16 + lr;
                    if (col < 41) out[(size_t)n * 41 + col] = m[ct] - mx - ls;
                }
            }
        }
    }
}

// ==================== CSR gather, PAIRS=32: 64 lanes = full row ====================
template<bool SCALE_OUT>
__global__ __launch_bounds__(256)
void gather32(const int* __restrict__ rowstart, const int* __restrict__ srcidx,
              const float* __restrict__ dinv, const uint_t* __restrict__ msg,
              const uint_t* __restrict__ pre, uint_t* __restrict__ outH, int N) {
    int gt = blockIdx.x * 256 + threadIdx.x;
    int n = gt >> 6;
    if (n >= N) return;
    const uint_t lo = (uint_t)(gt & 63);          // k*32+pair
    const int STR = 64;
    int beg = rowstart[n], end = rowstart[n + 1];
    float dn = dinv[n];
    size_t o = (size_t)n * STR + lo;
    uint_t p = 0;
    if (pre) p = pre[o];

    float ax0 = 0.f, ax1 = 0.f, ay0 = 0.f, ay1 = 0.f;
    int e = beg;
    for (; e + 8 <= end; e += 8) {
        int4 sa = *(const int4*)&srcidx[e];
        int4 sb = *(const int4*)&srcidx[e + 4];
        uint_t m0 = msg[(uint_t)(sa.x * STR) + lo];
        uint_t m1 = msg[(uint_t)(sa.y * STR) + lo];
        uint_t m2 = msg[(uint_t)(sa.z * STR) + lo];
        uint_t m3 = msg[(uint_t)(sa.w * STR) + lo];
        uint_t m4 = msg[(uint_t)(sb.x * STR) + lo];
        uint_t m5 = msg[(uint_t)(sb.y * STR) + lo];
        uint_t m6 = msg[(uint_t)(sb.z * STR) + lo];
        uint_t m7 = msg[(uint_t)(sb.w * STR) + lo];
        ax0 += __uint_as_float(m0 << 16); ay0 += __uint_as_float(m0 & 0xffff0000u);
        ax1 += __uint_as_float(m1 << 16); ay1 += __uint_as_float(m1 & 0xffff0000u);
        ax0 += __uint_as_float(m2 << 16); ay0 += __uint_as_float(m2 & 0xffff0000u);
        ax1 += __uint_as_float(m3 << 16); ay1 += __uint_as_float(m3 & 0xffff0000u);
        ax0 += __uint_as_float(m4 << 16); ay0 += __uint_as_float(m4 & 0xffff0000u);
        ax1 += __uint_as_float(m5 << 16); ay1 += __uint_as_float(m5 & 0xffff0000u);
        ax0 += __uint_as_float(m6 << 16); ay0 += __uint_as_float(m6 & 0xffff0000u);
        ax1 += __uint_as_float(m7 << 16); ay1 += __uint_as_float(m7 & 0xffff0000u);
    }
    if (e < end) {   // one 4-batch remains (rows padded to multiple of 4)
        int4 sa = *(const int4*)&srcidx[e];
        uint_t m0 = msg[(uint_t)(sa.x * STR) + lo];
        uint_t m1 = msg[(uint_t)(sa.y * STR) + lo];
        uint_t m2 = msg[(uint_t)(sa.z * STR) + lo];
        uint_t m3 = msg[(uint_t)(sa.w * STR) + lo];
        ax0 += __uint_as_float(m0 << 16); ay0 += __uint_as_float(m0 & 0xffff0000u);
        ax1 += __uint_as_float(m1 << 16); ay1 += __uint_as_float(m1 & 0xffff0000u);
        ax0 += __uint_as_float(m2 << 16); ay0 += __uint_as_float(m2 & 0xffff0000u);
        ax1 += __uint_as_float(m3 << 16); ay1 += __uint_as_float(m3 & 0xffff0000u);
    }
    float ax = (ax0 + ax1) * dn;
    float ay = (ay0 + ay1) * dn;
    if (pre) {
        ax = fmaxf(ax + bf2f((ushort_t)p), 0.0f);
        ay = fmaxf(ay + bf2f((ushort_t)(p >> 16)), 0.0f);
    }
    if (SCALE_OUT) { ax *= dn; ay *= dn; }
    outH[o] = pack2(ax, ay);
}

// ==================== CSR gather, row width 48: all 64 lanes active (n = gt/48) ====================
template<bool SCALE_OUT>
__global__ __launch_bounds__(256)
void gather24(const int* __restrict__ rowstart, const int* __restrict__ srcidx,
              const float* __restrict__ dinv, const uint_t* __restrict__ msg,
              const uint_t* __restrict__ pre, uint_t* __restrict__ outH, int N) {
    int gt = blockIdx.x * 256 + threadIdx.x;
    int n = gt / 48;
    if (n >= N) return;
    const uint_t lo = (uint_t)(gt - n * 48);      // k*24+pair in [0,48)
    const int STR = 48;
    int beg = rowstart[n], end = rowstart[n + 1];
    float dn = dinv[n];
    size_t o = (size_t)n * STR + lo;
    uint_t p = 0;
    if (pre) p = pre[o];

    float ax0 = 0.f, ax1 = 0.f, ay0 = 0.f, ay1 = 0.f;
    int e = beg;
    for (; e + 8 <= end; e += 8) {
        int4 sa = *(const int4*)&srcidx[e];
        int4 sb = *(const int4*)&srcidx[e + 4];
        uint_t m0 = msg[(uint_t)(sa.x * STR) + lo];
        uint_t m1 = msg[(uint_t)(sa.y * STR) + lo];
        uint_t m2 = msg[(uint_t)(sa.z * STR) + lo];
        uint_t m3 = msg[(uint_t)(sa.w * STR) + lo];
        uint_t m4 = msg[(uint_t)(sb.x * STR) + lo];
        uint_t m5 = msg[(uint_t)(sb.y * STR) + lo];
        uint_t m6 = msg[(uint_t)(sb.z * STR) + lo];
        uint_t m7 = msg[(uint_t)(sb.w * STR) + lo];
        ax0 += __uint_as_float(m0 << 16); ay0 += __uint_as_float(m0 & 0xffff0000u);
        ax1 += __uint_as_float(m1 << 16); ay1 += __uint_as_float(m1 & 0xffff0000u);
        ax0 += __uint_as_float(m2 << 16); ay0 += __uint_as_float(m2 & 0xffff0000u);
        ax1 += __uint_as_float(m3 << 16); ay1 += __uint_as_float(m3 & 0xffff0000u);
        ax0 += __uint_as_float(m4 << 16); ay0 += __uint_as_float(m4 & 0xffff0000u);
        ax1 += __uint_as_float(m5 << 16); ay1 += __uint_as_float(m5 & 0xffff0000u);
        ax0 += __uint_as_float(m6 << 16); ay0 += __uint_as_float(m6 & 0xffff0000u);
        ax1 += __uint_as_float(m7 << 16); ay1 += __uint_as_float(m7 & 0xffff0000u);
    }
    if (e < end) {
        int4 sa = *(const int4*)&srcidx[e];
        uint_t m0 = msg[(uint_t)(sa.x * STR) + lo];
        uint_t m1 = msg[(uint_t)(sa.y * STR) + lo];
        uint_t m2 = msg[(uint_t)(sa.z * STR) + lo];
        uint_t m3 = msg[(uint_t)(sa.w * STR) + lo];
        ax0 += __uint_as_float(m0 << 16); ay0 += __uint_as_float(m0 & 0xffff0000u);
        ax1 += __uint_as_float(m1 << 16); ay1 += __uint_as_float(m1 & 0xffff0000u);
        ax0 += __uint_as_float(m2 << 16); ay0 += __uint_as_float(m2 & 0xffff0000u);
        ax1 += __uint_as_float(m3 << 16); ay1 += __uint_as_float(m3 & 0xffff0000u);
    }
    float ax = (ax0 + ax1) * dn;
    float ay = (ay0 + ay1) * dn;
    if (pre) {
        ax = fmaxf(ax + bf2f((ushort_t)p), 0.0f);
        ay = fmaxf(ay + bf2f((ushort_t)(p >> 16)), 0.0f);
    }
    if (SCALE_OUT) { ax *= dn; ay *= dn; }
    outH[o] = pack2(ax, ay);
}

extern "C" void kernel_launch(void* const* d_in, const int* in_sizes, int n_in,
                              void* d_out, int out_size, void* d_ws, size_t ws_size,
                              hipStream_t stream) {
    const float* x       = (const float*)d_in[0];
    const int*   ei      = (const int*)  d_in[1];
    const float* w1_init = (const float*)d_in[2];
    const float* w1      = (const float*)d_in[3];
    const float* w1_root = (const float*)d_in[4];
    const float* b1      = (const float*)d_in[5];
    const float* w2_init = (const float*)d_in[6];
    const float* w2      = (const float*)d_in[7];
    const float* w2_root = (const float*)d_in[8];
    const float* b2      = (const float*)d_in[9];

    const int Fin1 = 128;
    int N = in_sizes[0] / Fin1;          // 100000
    int E = in_sizes[1] / 2;             // 1600000
    const int* row = ei;
    const int* col = ei + E;

    char* ws = (char*)d_ws;
    size_t off = 0;
    auto carve = [&](size_t bytes) -> void* {
        void* p = ws + off;
        off += (bytes + 255) & ~(size_t)255;
        return p;
    };
    int nblkN = (N + TPB - 1) / TPB;   // 391 (<=512 for one-block scan)
    int*      cnt      = (int*)     carve((size_t)N * 4);
    int*      incl     = (int*)     carve((size_t)N * 4);
    int*      rowstart = (int*)     carve((size_t)(N + 1) * 4);
    int*      bsum     = (int*)     carve((size_t)nblkN * 4);
    float*    dinv     = (float*)   carve((size_t)N * 4);
    unsigned short* pos = (unsigned short*)carve((size_t)E * 2);      // rank fits in u16
    int*      srcidx   = (int*)     carve((size_t)(E + 3 * (size_t)N + 64) * 4);  // padded CSR
    short*    swz      = (short*)   carve((size_t)(SWZ_A + SWZ_B + SWZ_C + SWZ_D) * 2);
    ushort_t* xh       = (ushort_t*)carve((size_t)N * 128 * 2);          // bf16 x
    ushort_t* hh       = (ushort_t*)carve((size_t)N * 64 * 2);           // bf16 h
    ushort_t* b16A     = (ushort_t*)carve((size_t)N * 2 * 64 * 2 + 256); // P / agg (+sentinel row)
    ushort_t* b16B     = (ushort_t*)carve((size_t)N * 2 * 64 * 2 + 256); // out_t   (+sentinel row)
    uint_t*   pre      = (uint_t*)  carve((size_t)N * 2 * 32 * 4);       // packed bf16 pre

    // ---- sentinel msg rows (PAIRS=32 layout) zeroed once ----
    hipMemsetAsync((char*)b16A + (size_t)N * 256, 0, 256, stream);
    hipMemsetAsync((char*)b16B + (size_t)N * 256, 0, 256, stream);
    hipMemsetAsync(cnt, 0, (size_t)N * 4, stream);

    // ---- fused preamble: rank || weight swizzle || x->bf16 ----
    int nEb = (E + TPB - 1) / TPB;                         // 6250
    int swztot = SWZ_A + SWZ_B + SWZ_C + SWZ_D;
    int nSb = (swztot + TPB - 1) / TPB;                    // 320
    int n4 = N * 128 / 4;
    int nCb = (n4 + TPB - 1) / TPB;                        // 12500
    pre1<<<nEb + nSb + nCb, TPB, 0, stream>>>(col, cnt, pos, E, nEb,
                                              w1_init, w1, w1_root, w2_init, w2, w2_root,
                                              swz, nSb, (const float4*)x, (uint2*)xh, n4);

    // ---- scan chain ----
    scan_block  <<<nblkN, TPB, 0, stream>>>(cnt, incl, bsum, N);
    scan_bsums  <<<1, 512, 0, stream>>>(bsum, nblkN);
    finalize_csr<<<nblkN, TPB, 0, stream>>>(incl, bsum, cnt, rowstart, dinv, N);

    const short* swzA = swz;
    const short* swzB = swz + SWZ_A;
    const short* swzC = swz + SWZ_A + SWZ_B;
    const short* swzD = swz + SWZ_A + SWZ_B + SWZ_C;
    dim3 gg1((N + 127) / 128, 1);
    int GB = (N + 127) / 128;                               // 782
    int g32 = (N * 64 + TPB - 1) / TPB;                     // 25000
    int g24 = (N * 48 + TPB - 1) / TPB;                     // 18750

    // ---- layer 1 t0 GEMM fused with CSR fill+pad (independent work, 2:6 interleave) ----
    int FBb = (E + N + TPB - 1) / TPB;                      // 6641
    int C1 = max((GB * 2 + 1) / 2, (FBb + 5) / 6);          // 1107
    gemm_t0_f<8, 4, 4><<<C1 * 8, TPB, 0, stream>>>(xh, 128, swzA, b1, dinv, 64, N,
                                                   pre, (uint_t*)b16A, GB, FBb,
                                                   row, col, rowstart, pos, cnt, srcidx, E);

    gather32<true ><<<g32, TPB, 0, stream>>>(rowstart, srcidx, dinv, (const uint_t*)b16A,
                                             pre, (uint_t*)b16B, N);
    gather32<false><<<g32, TPB, 0, stream>>>(rowstart, srcidx, dinv, (const uint_t*)b16B,
                                             nullptr, (uint_t*)b16A, N);
    gemm_t1_l1<<<gg1, TPB, 0, stream>>>(b16A, xh, swzB, b1 + 2 * 64, N, (uint_t*)hh);

    // ---- sentinel rows for width-48 layout (zero after L1 consumers are done) ----
    hipMemsetAsync((char*)b16A + (size_t)N * 192, 0, 192, stream);
    hipMemsetAsync((char*)b16B + (size_t)N * 192, 0, 192, stream);

    // ---- layer 2 (64 -> 41) ----
    gemm_t0_f<6, 3, 2><<<GB * 2, TPB, 0, stream>>>(hh, 64, swzC, b2, dinv, 41, N,
                                                   pre, (uint_t*)b16A, GB, 0,
                                                   nullptr, nullptr, nullptr, nullptr, nullptr, nullptr, 0);
    gather24<true ><<<g24, TPB, 0, stream>>>(rowstart, srcidx, dinv, (const uint_t*)b16A,
                                             pre, (uint_t*)b16B, N);
    gather24<false><<<g24, TPB, 0, stream>>>(rowstart, srcidx, dinv, (const uint_t*)b16B,
                                             nullptr, (uint_t*)b16A, N);
    gemm_t1_l2<<<gg1, TPB, 0, stream>>>(b16A, hh, swzD, b2 + 2 * 41, N, (float*)d_out);
}

// Round 7
// 571.916 us; speedup vs baseline: 1.0355x; 1.0355x over previous
//
#include <hip/hip_runtime.h>
#include <math.h>

#define TPB 256
typedef unsigned short ushort_t;
typedef unsigned int uint_t;
typedef __attribute__((ext_vector_type(8))) short bf16x8;
typedef __attribute__((ext_vector_type(4))) float f32x4;

__device__ __forceinline__ float bf2f(ushort_t h) {
    return __uint_as_float(((uint_t)h) << 16);
}
__device__ __forceinline__ ushort_t f2bf(float f) {
    uint_t u = __float_as_uint(f);
    u += 0x7fff + ((u >> 16) & 1);
    return (ushort_t)(u >> 16);
}
__device__ __forceinline__ uint_t pack2(float x, float y) {
    return (uint_t)f2bf(x) | ((uint_t)f2bf(y) << 16);
}

#define SWZ_A 32768
#define SWZ_B 24576
#define SWZ_C 12288
#define SWZ_D 12288

// ==================== fused preamble: rank (atomics) || weight swizzle || x->bf16 ====================
// rank is device-atomic-throughput bound (~24 G/s) with VALU/HBM idle; swz+cvt ride along free.
__global__ __launch_bounds__(256)
void pre1(const int* __restrict__ col, int* __restrict__ cnt, unsigned short* __restrict__ pos,
          int E, int nEb,
          const float* __restrict__ w1_init, const float* __restrict__ w1,
          const float* __restrict__ w1_root, const float* __restrict__ w2_init,
          const float* __restrict__ w2, const float* __restrict__ w2_root,
          short* __restrict__ swzdst, int nSb,
          const float4* __restrict__ x, uint2* __restrict__ xh, int n4) {
    int b = blockIdx.x;
    if (b < nEb) {
        int e = b * 256 + threadIdx.x;
        if (e < E) pos[e] = (unsigned short)atomicAdd(&cnt[col[e]], 1);
        return;
    }
    if (b < nEb + nSb) {
        int idx = (b - nEb) * 256 + threadIdx.x;
        int region, base, CH, CT;
        if (idx < SWZ_A)                          { region = 0; base = 0; CH = 4; CT = 8; }
        else if (idx < SWZ_A + SWZ_B)             { region = 1; base = SWZ_A; CH = 6; CT = 4; }
        else if (idx < SWZ_A + SWZ_B + SWZ_C)     { region = 2; base = SWZ_A + SWZ_B; CH = 2; CT = 6; }
        else if (idx < SWZ_A + SWZ_B + SWZ_C + SWZ_D)
                                                  { region = 3; base = SWZ_A + SWZ_B + SWZ_C; CH = 4; CT = 3; }
        else return;
        int r = idx - base;
        int j = r & 7, ln = (r >> 3) & 63;
        int rest = r >> 9;
        int ct = rest % CT, c = (rest / CT) % CH, k = rest / (CT * CH);
        int colm = ct * 16 + (ln & 15);
        int kl = (ln >> 4) * 8 + j;
        float v = 0.0f;
        if (region == 0) {              // L1-t0: x(128) -> [init(64) | root_t0(64)]
            int kk = c * 32 + kl;
            if (colm < 64)       v = w1_init[((size_t)k * 128 + kk) * 64 + colm];
            else                 v = w1_root[((size_t)k * 128 + kk) * 64 + (colm - 64)];
        } else if (region == 1) {       // L1-t1: c<2: agg(64)@w1 ; c>=2: x(128)@root_t1
            if (c < 2) { int kk = c * 32 + kl;        v = w1[((size_t)k * 64 + kk) * 64 + colm]; }
            else       { int kk = (c - 2) * 32 + kl;  v = w1_root[((size_t)(2 + k) * 128 + kk) * 64 + colm]; }
        } else if (region == 2) {       // L2-t0: h(64) -> [init(41,pad48) | root_t0(41,pad48)]
            int kk = c * 32 + kl;
            if (colm < 48) { if (colm < 41)           v = w2_init[((size_t)k * 64 + kk) * 41 + colm]; }
            else           { int c2 = colm - 48; if (c2 < 41) v = w2_root[((size_t)k * 64 + kk) * 41 + c2]; }
        } else {                        // L2-t1: c<2: agg(48,rows41)@w2 ; c>=2: h(64)@root_t1
            if (c < 2) { int kk = c * 32 + kl;       if (kk < 41 && colm < 41) v = w2[((size_t)k * 41 + kk) * 41 + colm]; }
            else       { int kk = (c - 2) * 32 + kl; if (colm < 41)            v = w2_root[((size_t)(2 + k) * 64 + kk) * 41 + colm]; }
        }
        swzdst[(size_t)base + r] = (short)f2bf(v);
        return;
    }
    int i = (b - nEb - nSb) * 256 + threadIdx.x;
    if (i < n4) {
        float4 v = x[i];
        xh[i] = make_uint2(pack2(v.x, v.y), pack2(v.z, v.w));
    }
}

// ==================== scan chain ====================
__global__ void scan_block(const int* __restrict__ cnt, int* __restrict__ incl,
                           int* __restrict__ bsum, int N) {
    __shared__ int s[TPB];
    int i = blockIdx.x * TPB + threadIdx.x;
    s[threadIdx.x] = (i < N) ? ((cnt[i] + 3) & ~3) : 0;   // padded counts
    __syncthreads();
    for (int d = 1; d < TPB; d <<= 1) {
        int t = (threadIdx.x >= d) ? s[threadIdx.x - d] : 0;
        __syncthreads();
        s[threadIdx.x] += t;
        __syncthreads();
    }
    if (i < N) incl[i] = s[threadIdx.x];
    if (threadIdx.x == TPB - 1) bsum[blockIdx.x] = s[TPB - 1];
}

__global__ void scan_bsums(int* __restrict__ bsum, int nb) {
    __shared__ int s[512];
    int t = threadIdx.x;
    int v = (t < nb) ? bsum[t] : 0;
    s[t] = v;
    __syncthreads();
    for (int d = 1; d < 512; d <<= 1) {
        int u = (t >= d) ? s[t - d] : 0;
        __syncthreads();
        s[t] += u;
        __syncthreads();
    }
    if (t < nb) bsum[t] = s[t] - v;
}

__global__ void finalize_csr(const int* __restrict__ incl, const int* __restrict__ bsum,
                             const int* __restrict__ cnt, int* __restrict__ rowstart,
                             float* __restrict__ dinv, int N) {
    int i = blockIdx.x * TPB + threadIdx.x;
    if (i < N) {
        rowstart[i + 1] = incl[i] + bsum[blockIdx.x];
        int d = cnt[i];
        dinv[i] = (d > 0) ? rsqrtf((float)d) : 0.0f;
    }
    if (i == 0) rowstart[0] = 0;
}

__global__ void fill_csr(const int* __restrict__ row, const int* __restrict__ col,
                         const int* __restrict__ rowstart, const unsigned short* __restrict__ pos,
                         int* __restrict__ srcidx, int E) {
    int e = blockIdx.x * blockDim.x + threadIdx.x;
    if (e < E) srcidx[rowstart[col[e]] + (int)pos[e]] = row[e];
}

__global__ void pad_csr(const int* __restrict__ rowstart, const int* __restrict__ cnt,
                        int* __restrict__ srcidx, int N) {
    int i = blockIdx.x * blockDim.x + threadIdx.x;
    if (i >= N) return;
    int b = rowstart[i] + cnt[i], en = rowstart[i + 1];
    for (int e = b; e < en; ++e) srcidx[e] = N;
}

// ==================== t0 GEMM (per-k): s2 @ [Wa | Wb] -> outH (scaled by dinv) + pre ====================
template<int CT, int CTA, int CH>
__global__ __launch_bounds__(256, 4)
void gemm_t0(const ushort_t* __restrict__ s2, int s2s, const short* __restrict__ fragbuf,
             const float* __restrict__ biasB, const float* __restrict__ dinv,
             int FB, int N, uint_t* __restrict__ pre, uint_t* __restrict__ outH) {
    constexpr int PP = (CT - CTA) * 8;
    constexpr int PA = CTA * 8;
    const int k = blockIdx.y;
    const int n0 = blockIdx.x * 128;
    const int t = threadIdx.x;
    const int w = t >> 6, lane = t & 63, quad = lane >> 4, lr = lane & 15;
    const short* fb = fragbuf + (size_t)k * CH * CT * 512;

    int r0 = n0 + w * 32 + lr;
    int m0 = r0 < N ? r0 : N - 1;
    int m1 = (r0 + 16) < N ? (r0 + 16) : N - 1;

    // hoisted A loads: all in flight before staging
    bf16x8 a0v[CH], a1v[CH];
#pragma unroll
    for (int c = 0; c < CH; ++c) {
        int off = c * 32 + quad * 8;
        a0v[c] = *(const bf16x8*)&s2[(size_t)m0 * s2s + off];
        a1v[c] = *(const bf16x8*)&s2[(size_t)m1 * s2s + off];
    }

    __shared__ short lds_b[CH * CT * 512];
    {
        constexpr int CHUNKS = CH * CT * 64;   // bf16x8 chunks
#pragma unroll
        for (int i = 0; i < (CHUNKS + 255) / 256; ++i) {
            int idx = i * 256 + t;
            if (CHUNKS % 256 == 0 || idx < CHUNKS)
                *(bf16x8*)&lds_b[idx * 8] = *(const bf16x8*)&fb[(size_t)idx * 8];
        }
    }
    __syncthreads();

    f32x4 acc[2][CT];
#pragma unroll
    for (int rt = 0; rt < 2; ++rt)
#pragma unroll
        for (int ct = 0; ct < CT; ++ct) acc[rt][ct] = (f32x4){0.f, 0.f, 0.f, 0.f};

#pragma unroll
    for (int c = 0; c < CH; ++c) {
#pragma unroll
        for (int ct = 0; ct < CT; ++ct) {
            bf16x8 bfr = *(const bf16x8*)&lds_b[((size_t)c * CT + ct) * 512 + lane * 8];
            acc[0][ct] = __builtin_amdgcn_mfma_f32_16x16x32_bf16(a0v[c], bfr, acc[0][ct], 0, 0, 0);
            acc[1][ct] = __builtin_amdgcn_mfma_f32_16x16x32_bf16(a1v[c], bfr, acc[1][ct], 0, 0, 0);
        }
    }

#pragma unroll
    for (int rt = 0; rt < 2; ++rt) {
#pragma unroll
        for (int i = 0; i < 4; ++i) {
            int n = n0 + w * 32 + rt * 16 + quad * 4 + i;
            if (n >= N) continue;
            float dnv = dinv[n];
#pragma unroll
            for (int ct = 0; ct < CT; ++ct) {
                int col = ct * 16 + lr;
                float v = acc[rt][ct][i];
                if (ct < CTA) {
                    v *= dnv;                       // pre-scale msg by dinv[src]
                } else {
                    int c2 = col - CTA * 16;
                    if (c2 < FB) v += biasB[(size_t)k * FB + c2];
                }
                float vn = __shfl_xor(v, 1);
                uint_t p = pack2(v, vn);
                uint_t p2 = __shfl_xor(p, 2);
                if (!(lr & 3)) {
                    if (ct < CTA) {
                        *(uint2*)&outH[((size_t)n * 2 + k) * PA + (col >> 1)] = make_uint2(p, p2);
                    } else {
                        int c2 = col - CTA * 16;
                        *(uint2*)&pre[((size_t)n * 2 + k) * PP + (c2 >> 1)] = make_uint2(p, p2);
                    }
                }
            }
        }
    }
}

// ==================== t1 GEMM layer1: relu+mean -> hh bf16 ====================
__global__ __launch_bounds__(256, 3)
void gemm_t1_l1(const ushort_t* __restrict__ s1, const ushort_t* __restrict__ xh,
                const short* __restrict__ fragbuf, const float* __restrict__ bias,
                int N, uint_t* __restrict__ hhU) {
    constexpr int CT = 4, CH = 6;
    const int n0 = blockIdx.x * 128;
    const int t = threadIdx.x;
    const int w = t >> 6, lane = t & 63, quad = lane >> 4, lr = lane & 15;

    int r0 = n0 + w * 32 + lr;
    int m0 = r0 < N ? r0 : N - 1;
    int m1 = (r0 + 16) < N ? (r0 + 16) : N - 1;

    // hoisted A loads
    bf16x8 s0a[2][2], s1a[2][2];   // [c][k]
    bf16x8 x0a[4], x1a[4];
#pragma unroll
    for (int c = 0; c < 2; ++c) {
        int off = c * 32 + quad * 8;
#pragma unroll
        for (int kk = 0; kk < 2; ++kk) {
            s0a[c][kk] = *(const bf16x8*)&s1[((size_t)m0 * 2 + kk) * 64 + off];
            s1a[c][kk] = *(const bf16x8*)&s1[((size_t)m1 * 2 + kk) * 64 + off];
        }
    }
#pragma unroll
    for (int c = 0; c < 4; ++c) {
        int off = c * 32 + quad * 8;
        x0a[c] = *(const bf16x8*)&xh[(size_t)m0 * 128 + off];
        x1a[c] = *(const bf16x8*)&xh[(size_t)m1 * 128 + off];
    }

    __shared__ short lds_b[2 * CH * CT * 512];   // 48 KB, both k
    {
        constexpr int CHUNKS = 2 * CH * CT * 64;
#pragma unroll
        for (int i = 0; i < CHUNKS / 256; ++i) {
            int idx = i * 256 + t;
            *(bf16x8*)&lds_b[idx * 8] = *(const bf16x8*)&fragbuf[(size_t)idx * 8];
        }
    }
    __syncthreads();

    f32x4 acc[2][2][CT];
#pragma unroll
    for (int k = 0; k < 2; ++k)
#pragma unroll
        for (int rt = 0; rt < 2; ++rt)
#pragma unroll
            for (int ct = 0; ct < CT; ++ct) acc[k][rt][ct] = (f32x4){0.f, 0.f, 0.f, 0.f};

#pragma unroll
    for (int c = 0; c < CH; ++c) {
#pragma unroll
        for (int k = 0; k < 2; ++k) {
            bf16x8 a0 = (c < 2) ? s0a[c][k] : x0a[c - 2];
            bf16x8 a1 = (c < 2) ? s1a[c][k] : x1a[c - 2];
#pragma unroll
            for (int ct = 0; ct < CT; ++ct) {
                bf16x8 b = *(const bf16x8*)&lds_b[(((size_t)k * CH + c) * CT + ct) * 512 + lane * 8];
                acc[k][0][ct] = __builtin_amdgcn_mfma_f32_16x16x32_bf16(a0, b, acc[k][0][ct], 0, 0, 0);
                acc[k][1][ct] = __builtin_amdgcn_mfma_f32_16x16x32_bf16(a1, b, acc[k][1][ct], 0, 0, 0);
            }
        }
    }

#pragma unroll
    for (int rt = 0; rt < 2; ++rt) {
#pragma unroll
        for (int i = 0; i < 4; ++i) {
            int n = n0 + w * 32 + rt * 16 + quad * 4 + i;
            if (n >= N) continue;
#pragma unroll
            for (int ct = 0; ct < CT; ++ct) {
                int col = ct * 16 + lr;
                float v0 = fmaxf(acc[0][rt][ct][i] + bias[col], 0.0f);
                float v1 = fmaxf(acc[1][rt][ct][i] + bias[64 + col], 0.0f);
                float m = 0.5f * (v0 + v1);
                float mn = __shfl_xor(m, 1);
                uint_t p = pack2(m, mn);
                uint_t p2 = __shfl_xor(p, 2);
                if (!(lr & 3)) *(uint2*)&hhU[(size_t)n * 32 + (col >> 1)] = make_uint2(p, p2);
            }
        }
    }
}

// ===== t1 GEMM layer2: relu+mean+log_softmax -> d_out f32 =====
__global__ __launch_bounds__(256, 3)
void gemm_t1_l2(const ushort_t* __restrict__ s1, const ushort_t* __restrict__ hh,
                const short* __restrict__ fragbuf, const float* __restrict__ bias,
                int N, float* __restrict__ out) {
    constexpr int CT = 3, CH = 4;
    const int n0 = blockIdx.x * 128;
    const int t = threadIdx.x;
    const int w = t >> 6, lane = t & 63, quad = lane >> 4, lr = lane & 15;

    int r0 = n0 + w * 32 + lr;
    int m0 = r0 < N ? r0 : N - 1;
    int m1 = (r0 + 16) < N ? (r0 + 16) : N - 1;

    bf16x8 s0a[2][2], s1a[2][2];   // [c][k]
    bf16x8 h0a[2], h1a[2];
#pragma unroll
    for (int c = 0; c < 2; ++c) {
        int off = c * 32 + quad * 8;
#pragma unroll
        for (int kk = 0; kk < 2; ++kk) {
            s0a[c][kk] = *(const bf16x8*)&s1[((size_t)m0 * 2 + kk) * 48 + off];
            s1a[c][kk] = *(const bf16x8*)&s1[((size_t)m1 * 2 + kk) * 48 + off];
        }
    }
#pragma unroll
    for (int c = 0; c < 2; ++c) {
        int off = c * 32 + quad * 8;
        h0a[c] = *(const bf16x8*)&hh[(size_t)m0 * 64 + off];
        h1a[c] = *(const bf16x8*)&hh[(size_t)m1 * 64 + off];
    }

    __shared__ short lds_b[2 * CH * CT * 512];   // 24 KB, both k
    {
        constexpr int CHUNKS = 2 * CH * CT * 64;
#pragma unroll
        for (int i = 0; i < CHUNKS / 256; ++i) {
            int idx = i * 256 + t;
            *(bf16x8*)&lds_b[idx * 8] = *(const bf16x8*)&fragbuf[(size_t)idx * 8];
        }
    }
    __syncthreads();

    f32x4 acc[2][2][CT];
#pragma unroll
    for (int k = 0; k < 2; ++k)
#pragma unroll
        for (int rt = 0; rt < 2; ++rt)
#pragma unroll
            for (int ct = 0; ct < CT; ++ct) acc[k][rt][ct] = (f32x4){0.f, 0.f, 0.f, 0.f};

#pragma unroll
    for (int c = 0; c < CH; ++c) {
#pragma unroll
        for (int k = 0; k < 2; ++k) {
            bf16x8 a0 = (c < 2) ? s0a[c][k] : h0a[c - 2];
            bf16x8 a1 = (c < 2) ? s1a[c][k] : h1a[c - 2];
#pragma unroll
            for (int ct = 0; ct < CT; ++ct) {
                bf16x8 b = *(const bf16x8*)&lds_b[(((size_t)k * CH + c) * CT + ct) * 512 + lane * 8];
                acc[k][0][ct] = __builtin_amdgcn_mfma_f32_16x16x32_bf16(a0, b, acc[k][0][ct], 0, 0, 0);
                acc[k][1][ct] = __builtin_amdgcn_mfma_f32_16x16x32_bf16(a1, b, acc[k][1][ct], 0, 0, 0);
            }
        }
    }

#pragma unroll
    for (int rt = 0; rt < 2; ++rt) {
#pragma unroll
        for (int i = 0; i < 4; ++i) {
            int n = n0 + w * 32 + rt * 16 + quad * 4 + i;
            float m[CT];
            float mx = -1e30f;
#pragma unroll
            for (int ct = 0; ct < CT; ++ct) {
                int col = ct * 16 + lr;
                float b0 = (col < 41) ? bias[col] : 0.0f;
                float b1v = (col < 41) ? bias[41 + col] : 0.0f;
                float v0 = fmaxf(acc[0][rt][ct][i] + b0, 0.0f);
                float v1 = fmaxf(acc[1][rt][ct][i] + b1v, 0.0f);
                m[ct] = 0.5f * (v0 + v1);
                if (col < 41) mx = fmaxf(mx, m[ct]);
            }
#pragma unroll
            for (int msk = 1; msk < 16; msk <<= 1) mx = fmaxf(mx, __shfl_xor(mx, msk));
            float s = 0.0f;
#pragma unroll
            for (int ct = 0; ct < CT; ++ct) {
                int col = ct * 16 + lr;
                if (col < 41) s += __expf(m[ct] - mx);
            }
#pragma unroll
            for (int msk = 1; msk < 16; msk <<= 1) s += __shfl_xor(s, msk);
            float ls = __logf(s);
            if (n < N) {
#pragma unroll
                for (int ct = 0; ct < CT; ++ct) {
                    int col = ct * 16 + lr;
                    if (col < 41) out[(size_t)n * 41 + col] = m[ct] - mx - ls;
                }
            }
        }
    }
}

// ==================== CSR gather, width 64: wave = full row ====================
template<bool SCALE_OUT>
__global__ __launch_bounds__(256)
void gather32(const int* __restrict__ rowstart, const int* __restrict__ srcidx,
              const float* __restrict__ dinv, const uint_t* __restrict__ msg,
              const uint_t* __restrict__ pre, uint_t* __restrict__ outH, int N) {
    int gt = blockIdx.x * 256 + threadIdx.x;
    int n = gt >> 6;
    if (n >= N) return;
    const uint_t lo = (uint_t)(gt & 63);          // k*32+pair
    const int STR = 64;
    int beg = rowstart[n], end = rowstart[n + 1];
    float dn = dinv[n];
    size_t o = (size_t)n * STR + lo;
    uint_t p = 0;
    if (pre) p = pre[o];

    float ax0 = 0.f, ax1 = 0.f, ay0 = 0.f, ay1 = 0.f;
    int e = beg;
    for (; e + 8 <= end; e += 8) {
        int4 sa = *(const int4*)&srcidx[e];
        int4 sb = *(const int4*)&srcidx[e + 4];
        uint_t m0 = msg[(uint_t)(sa.x * STR) + lo];
        uint_t m1 = msg[(uint_t)(sa.y * STR) + lo];
        uint_t m2 = msg[(uint_t)(sa.z * STR) + lo];
        uint_t m3 = msg[(uint_t)(sa.w * STR) + lo];
        uint_t m4 = msg[(uint_t)(sb.x * STR) + lo];
        uint_t m5 = msg[(uint_t)(sb.y * STR) + lo];
        uint_t m6 = msg[(uint_t)(sb.z * STR) + lo];
        uint_t m7 = msg[(uint_t)(sb.w * STR) + lo];
        ax0 += __uint_as_float(m0 << 16); ay0 += __uint_as_float(m0 & 0xffff0000u);
        ax1 += __uint_as_float(m1 << 16); ay1 += __uint_as_float(m1 & 0xffff0000u);
        ax0 += __uint_as_float(m2 << 16); ay0 += __uint_as_float(m2 & 0xffff0000u);
        ax1 += __uint_as_float(m3 << 16); ay1 += __uint_as_float(m3 & 0xffff0000u);
        ax0 += __uint_as_float(m4 << 16); ay0 += __uint_as_float(m4 & 0xffff0000u);
        ax1 += __uint_as_float(m5 << 16); ay1 += __uint_as_float(m5 & 0xffff0000u);
        ax0 += __uint_as_float(m6 << 16); ay0 += __uint_as_float(m6 & 0xffff0000u);
        ax1 += __uint_as_float(m7 << 16); ay1 += __uint_as_float(m7 & 0xffff0000u);
    }
    if (e < end) {   // one 4-batch remains (rows padded to multiple of 4)
        int4 sa = *(const int4*)&srcidx[e];
        uint_t m0 = msg[(uint_t)(sa.x * STR) + lo];
        uint_t m1 = msg[(uint_t)(sa.y * STR) + lo];
        uint_t m2 = msg[(uint_t)(sa.z * STR) + lo];
        uint_t m3 = msg[(uint_t)(sa.w * STR) + lo];
        ax0 += __uint_as_float(m0 << 16); ay0 += __uint_as_float(m0 & 0xffff0000u);
        ax1 += __uint_as_float(m1 << 16); ay1 += __uint_as_float(m1 & 0xffff0000u);
        ax0 += __uint_as_float(m2 << 16); ay0 += __uint_as_float(m2 & 0xffff0000u);
        ax1 += __uint_as_float(m3 << 16); ay1 += __uint_as_float(m3 & 0xffff0000u);
    }
    float ax = (ax0 + ax1) * dn;
    float ay = (ay0 + ay1) * dn;
    if (pre) {
        ax = fmaxf(ax + bf2f((ushort_t)p), 0.0f);
        ay = fmaxf(ay + bf2f((ushort_t)(p >> 16)), 0.0f);
    }
    if (SCALE_OUT) { ax *= dn; ay *= dn; }
    outH[o] = pack2(ax, ay);
}

// ==================== CSR gather, row width 48: all 64 lanes active (n = gt/48) ====================
template<bool SCALE_OUT>
__global__ __launch_bounds__(256)
void gather24(const int* __restrict__ rowstart, const int* __restrict__ srcidx,
              const float* __restrict__ dinv, const uint_t* __restrict__ msg,
              const uint_t* __restrict__ pre, uint_t* __restrict__ outH, int N) {
    int gt = blockIdx.x * 256 + threadIdx.x;
    int n = gt / 48;
    if (n >= N) return;
    const uint_t lo = (uint_t)(gt - n * 48);      // k*24+pair in [0,48)
    const int STR = 48;
    int beg = rowstart[n], end = rowstart[n + 1];
    float dn = dinv[n];
    size_t o = (size_t)n * STR + lo;
    uint_t p = 0;
    if (pre) p = pre[o];

    float ax0 = 0.f, ax1 = 0.f, ay0 = 0.f, ay1 = 0.f;
    int e = beg;
    for (; e + 8 <= end; e += 8) {
        int4 sa = *(const int4*)&srcidx[e];
        int4 sb = *(const int4*)&srcidx[e + 4];
        uint_t m0 = msg[(uint_t)(sa.x * STR) + lo];
        uint_t m1 = msg[(uint_t)(sa.y * STR) + lo];
        uint_t m2 = msg[(uint_t)(sa.z * STR) + lo];
        uint_t m3 = msg[(uint_t)(sa.w * STR) + lo];
        uint_t m4 = msg[(uint_t)(sb.x * STR) + lo];
        uint_t m5 = msg[(uint_t)(sb.y * STR) + lo];
        uint_t m6 = msg[(uint_t)(sb.z * STR) + lo];
        uint_t m7 = msg[(uint_t)(sb.w * STR) + lo];
        ax0 += __uint_as_float(m0 << 16); ay0 += __uint_as_float(m0 & 0xffff0000u);
        ax1 += __uint_as_float(m1 << 16); ay1 += __uint_as_float(m1 & 0xffff0000u);
        ax0 += __uint_as_float(m2 << 16); ay0 += __uint_as_float(m2 & 0xffff0000u);
        ax1 += __uint_as_float(m3 << 16); ay1 += __uint_as_float(m3 & 0xffff0000u);
        ax0 += __uint_as_float(m4 << 16); ay0 += __uint_as_float(m4 & 0xffff0000u);
        ax1 += __uint_as_float(m5 << 16); ay1 += __uint_as_float(m5 & 0xffff0000u);
        ax0 += __uint_as_float(m6 << 16); ay0 += __uint_as_float(m6 & 0xffff0000u);
        ax1 += __uint_as_float(m7 << 16); ay1 += __uint_as_float(m7 & 0xffff0000u);
    }
    if (e < end) {
        int4 sa = *(const int4*)&srcidx[e];
        uint_t m0 = msg[(uint_t)(sa.x * STR) + lo];
        uint_t m1 = msg[(uint_t)(sa.y * STR) + lo];
        uint_t m2 = msg[(uint_t)(sa.z * STR) + lo];
        uint_t m3 = msg[(uint_t)(sa.w * STR) + lo];
        ax0 += __uint_as_float(m0 << 16); ay0 += __uint_as_float(m0 & 0xffff0000u);
        ax1 += __uint_as_float(m1 << 16); ay1 += __uint_as_float(m1 & 0xffff0000u);
        ax0 += __uint_as_float(m2 << 16); ay0 += __uint_as_float(m2 & 0xffff0000u);
        ax1 += __uint_as_float(m3 << 16); ay1 += __uint_as_float(m3 & 0xffff0000u);
    }
    float ax = (ax0 + ax1) * dn;
    float ay = (ay0 + ay1) * dn;
    if (pre) {
        ax = fmaxf(ax + bf2f((ushort_t)p), 0.0f);
        ay = fmaxf(ay + bf2f((ushort_t)(p >> 16)), 0.0f);
    }
    if (SCALE_OUT) { ax *= dn; ay *= dn; }
    outH[o] = pack2(ax, ay);
}

extern "C" void kernel_launch(void* const* d_in, const int* in_sizes, int n_in,
                              void* d_out, int out_size, void* d_ws, size_t ws_size,
                              hipStream_t stream) {
    const float* x       = (const float*)d_in[0];
    const int*   ei      = (const int*)  d_in[1];
    const float* w1_init = (const float*)d_in[2];
    const float* w1      = (const float*)d_in[3];
    const float* w1_root = (const float*)d_in[4];
    const float* b1      = (const float*)d_in[5];
    const float* w2_init = (const float*)d_in[6];
    const float* w2      = (const float*)d_in[7];
    const float* w2_root = (const float*)d_in[8];
    const float* b2      = (const float*)d_in[9];

    const int Fin1 = 128;
    int N = in_sizes[0] / Fin1;          // 100000
    int E = in_sizes[1] / 2;             // 1600000
    const int* row = ei;
    const int* col = ei + E;

    char* ws = (char*)d_ws;
    size_t off = 0;
    auto carve = [&](size_t bytes) -> void* {
        void* p = ws + off;
        off += (bytes + 255) & ~(size_t)255;
        return p;
    };
    int nblkN = (N + TPB - 1) / TPB;   // 391 (<=512 for one-block scan)
    int*      cnt      = (int*)     carve((size_t)N * 4);
    int*      incl     = (int*)     carve((size_t)N * 4);
    int*      rowstart = (int*)     carve((size_t)(N + 1) * 4);
    int*      bsum     = (int*)     carve((size_t)nblkN * 4);
    float*    dinv     = (float*)   carve((size_t)N * 4);
    unsigned short* pos = (unsigned short*)carve((size_t)E * 2);      // rank fits in u16
    int*      srcidx   = (int*)     carve((size_t)(E + 3 * (size_t)N + 64) * 4);  // padded CSR
    short*    swz      = (short*)   carve((size_t)(SWZ_A + SWZ_B + SWZ_C + SWZ_D) * 2);
    ushort_t* xh       = (ushort_t*)carve((size_t)N * 128 * 2);          // bf16 x
    ushort_t* hh       = (ushort_t*)carve((size_t)N * 64 * 2);           // bf16 h
    ushort_t* b16A     = (ushort_t*)carve((size_t)N * 2 * 64 * 2 + 256); // P / agg (+sentinel row)
    ushort_t* b16B     = (ushort_t*)carve((size_t)N * 2 * 64 * 2 + 256); // out_t   (+sentinel row)
    uint_t*   pre      = (uint_t*)  carve((size_t)N * 2 * 32 * 4);       // packed bf16 pre

    // ---- sentinel msg rows (width-64 layout) + cnt zeroed ----
    hipMemsetAsync((char*)b16A + (size_t)N * 256, 0, 256, stream);
    hipMemsetAsync((char*)b16B + (size_t)N * 256, 0, 256, stream);
    hipMemsetAsync(cnt, 0, (size_t)N * 4, stream);

    // ---- fused preamble: rank || weight swizzle || x->bf16 ----
    int nEb = (E + TPB - 1) / TPB;                         // 6250
    int swztot = SWZ_A + SWZ_B + SWZ_C + SWZ_D;
    int nSb = (swztot + TPB - 1) / TPB;                    // 320
    int n4 = N * 128 / 4;
    int nCb = (n4 + TPB - 1) / TPB;                        // 12500
    pre1<<<nEb + nSb + nCb, TPB, 0, stream>>>(col, cnt, pos, E, nEb,
                                              w1_init, w1, w1_root, w2_init, w2, w2_root,
                                              swz, nSb, (const float4*)x, (uint2*)xh, n4);

    // ---- scan chain + CSR fill ----
    scan_block  <<<nblkN, TPB, 0, stream>>>(cnt, incl, bsum, N);
    scan_bsums  <<<1, 512, 0, stream>>>(bsum, nblkN);
    finalize_csr<<<nblkN, TPB, 0, stream>>>(incl, bsum, cnt, rowstart, dinv, N);
    pad_csr     <<<nblkN, TPB, 0, stream>>>(rowstart, cnt, srcidx, N);
    fill_csr    <<<(E + TPB - 1) / TPB, TPB, 0, stream>>>(row, col, rowstart, pos, srcidx, E);

    const short* swzA = swz;
    const short* swzB = swz + SWZ_A;
    const short* swzC = swz + SWZ_A + SWZ_B;
    const short* swzD = swz + SWZ_A + SWZ_B + SWZ_C;
    dim3 gg2((N + 127) / 128, 2);
    dim3 gg1((N + 127) / 128, 1);
    int g32 = (N * 64 + TPB - 1) / TPB;                     // 25000
    int g24 = (N * 48 + TPB - 1) / TPB;                     // 18750

    // ---- layer 1 (128 -> 64) ----
    gemm_t0<8, 4, 4><<<gg2, TPB, 0, stream>>>(xh, 128, swzA, b1, dinv, 64, N, pre, (uint_t*)b16A);
    gather32<true ><<<g32, TPB, 0, stream>>>(rowstart, srcidx, dinv, (const uint_t*)b16A,
                                             pre, (uint_t*)b16B, N);
    gather32<false><<<g32, TPB, 0, stream>>>(rowstart, srcidx, dinv, (const uint_t*)b16B,
                                             nullptr, (uint_t*)b16A, N);
    gemm_t1_l1<<<gg1, TPB, 0, stream>>>(b16A, xh, swzB, b1 + 2 * 64, N, (uint_t*)hh);

    // ---- sentinel rows for width-48 layout (zero after L1 consumers are done) ----
    hipMemsetAsync((char*)b16A + (size_t)N * 192, 0, 192, stream);
    hipMemsetAsync((char*)b16B + (size_t)N * 192, 0, 192, stream);

    // ---- layer 2 (64 -> 41) ----
    gemm_t0<6, 3, 2><<<gg2, TPB, 0, stream>>>(hh, 64, swzC, b2, dinv, 41, N, pre, (uint_t*)b16A);
    gather24<true ><<<g24, TPB, 0, stream>>>(rowstart, srcidx, dinv, (const uint_t*)b16A,
                                             pre, (uint_t*)b16B, N);
    gather24<false><<<g24, TPB, 0, stream>>>(rowstart, srcidx, dinv, (const uint_t*)b16B,
                                             nullptr, (uint_t*)b16A, N);
    gemm_t1_l2<<<gg1, TPB, 0, stream>>>(b16A, hh, swzD, b2 + 2 * 41, N, (float*)d_out);
}

// Round 8
// 560.942 us; speedup vs baseline: 1.0558x; 1.0196x over previous
//
#include <hip/hip_runtime.h>
#include <math.h>

#define TPB 256
typedef unsigned short ushort_t;
typedef unsigned int uint_t;
typedef __attribute__((ext_vector_type(8))) short bf16x8;
typedef __attribute__((ext_vector_type(4))) float f32x4;

__device__ __forceinline__ float bf2f(ushort_t h) {
    return __uint_as_float(((uint_t)h) << 16);
}
__device__ __forceinline__ ushort_t f2bf(float f) {
    uint_t u = __float_as_uint(f);
    u += 0x7fff + ((u >> 16) & 1);
    return (ushort_t)(u >> 16);
}
__device__ __forceinline__ uint_t pack2(float x, float y) {
    return (uint_t)f2bf(x) | ((uint_t)f2bf(y) << 16);
}

#define SWZ_A 32768
#define SWZ_B 24576
#define SWZ_C 12288
#define SWZ_D 12288

// ==================== fused preamble: rank (atomics) || weight swizzle || x->bf16 ====================
__global__ __launch_bounds__(256)
void pre1(const int* __restrict__ col, int* __restrict__ cnt, unsigned short* __restrict__ pos,
          int E, int nEb,
          const float* __restrict__ w1_init, const float* __restrict__ w1,
          const float* __restrict__ w1_root, const float* __restrict__ w2_init,
          const float* __restrict__ w2, const float* __restrict__ w2_root,
          short* __restrict__ swzdst, int nSb,
          const float4* __restrict__ x, uint2* __restrict__ xh, int n4) {
    int b = blockIdx.x;
    if (b < nEb) {
        int e = b * 256 + threadIdx.x;
        if (e < E) pos[e] = (unsigned short)atomicAdd(&cnt[col[e]], 1);
        return;
    }
    if (b < nEb + nSb) {
        int idx = (b - nEb) * 256 + threadIdx.x;
        int region, base, CH, CT;
        if (idx < SWZ_A)                          { region = 0; base = 0; CH = 4; CT = 8; }
        else if (idx < SWZ_A + SWZ_B)             { region = 1; base = SWZ_A; CH = 6; CT = 4; }
        else if (idx < SWZ_A + SWZ_B + SWZ_C)     { region = 2; base = SWZ_A + SWZ_B; CH = 2; CT = 6; }
        else if (idx < SWZ_A + SWZ_B + SWZ_C + SWZ_D)
                                                  { region = 3; base = SWZ_A + SWZ_B + SWZ_C; CH = 4; CT = 3; }
        else return;
        int r = idx - base;
        int j = r & 7, ln = (r >> 3) & 63;
        int rest = r >> 9;
        int ct = rest % CT, c = (rest / CT) % CH, k = rest / (CT * CH);
        int colm = ct * 16 + (ln & 15);
        int kl = (ln >> 4) * 8 + j;
        float v = 0.0f;
        if (region == 0) {              // L1-t0: x(128) -> [init(64) | root_t0(64)]
            int kk = c * 32 + kl;
            if (colm < 64)       v = w1_init[((size_t)k * 128 + kk) * 64 + colm];
            else                 v = w1_root[((size_t)k * 128 + kk) * 64 + (colm - 64)];
        } else if (region == 1) {       // L1-t1: c<2: agg(64)@w1 ; c>=2: x(128)@root_t1
            if (c < 2) { int kk = c * 32 + kl;        v = w1[((size_t)k * 64 + kk) * 64 + colm]; }
            else       { int kk = (c - 2) * 32 + kl;  v = w1_root[((size_t)(2 + k) * 128 + kk) * 64 + colm]; }
        } else if (region == 2) {       // L2-t0: h(64) -> [init(41,pad48) | root_t0(41,pad48)]
            int kk = c * 32 + kl;
            if (colm < 48) { if (colm < 41)           v = w2_init[((size_t)k * 64 + kk) * 41 + colm]; }
            else           { int c2 = colm - 48; if (c2 < 41) v = w2_root[((size_t)k * 64 + kk) * 41 + c2]; }
        } else {                        // L2-t1: c<2: agg(48,rows41)@w2 ; c>=2: h(64)@root_t1
            if (c < 2) { int kk = c * 32 + kl;       if (kk < 41 && colm < 41) v = w2[((size_t)k * 41 + kk) * 41 + colm]; }
            else       { int kk = (c - 2) * 32 + kl; if (colm < 41)            v = w2_root[((size_t)(2 + k) * 64 + kk) * 41 + colm]; }
        }
        swzdst[(size_t)base + r] = (short)f2bf(v);
        return;
    }
    int i = (b - nEb - nSb) * 256 + threadIdx.x;
    if (i < n4) {
        float4 v = x[i];
        xh[i] = make_uint2(pack2(v.x, v.y), pack2(v.z, v.w));
    }
}

// ==================== scan chain ====================
__global__ void scan_block(const int* __restrict__ cnt, int* __restrict__ incl,
                           int* __restrict__ bsum, int N) {
    __shared__ int s[TPB];
    int i = blockIdx.x * TPB + threadIdx.x;
    s[threadIdx.x] = (i < N) ? ((cnt[i] + 3) & ~3) : 0;   // padded counts
    __syncthreads();
    for (int d = 1; d < TPB; d <<= 1) {
        int t = (threadIdx.x >= d) ? s[threadIdx.x - d] : 0;
        __syncthreads();
        s[threadIdx.x] += t;
        __syncthreads();
    }
    if (i < N) incl[i] = s[threadIdx.x];
    if (threadIdx.x == TPB - 1) bsum[blockIdx.x] = s[TPB - 1];
}

__global__ void scan_bsums(int* __restrict__ bsum, int nb) {
    __shared__ int s[512];
    int t = threadIdx.x;
    int v = (t < nb) ? bsum[t] : 0;
    s[t] = v;
    __syncthreads();
    for (int d = 1; d < 512; d <<= 1) {
        int u = (t >= d) ? s[t - d] : 0;
        __syncthreads();
        s[t] += u;
        __syncthreads();
    }
    if (t < nb) bsum[t] = s[t] - v;
}

__global__ void finalize_csr(const int* __restrict__ incl, const int* __restrict__ bsum,
                             const int* __restrict__ cnt, int* __restrict__ rowstart,
                             float* __restrict__ dinv, int N) {
    int i = blockIdx.x * TPB + threadIdx.x;
    if (i < N) {
        rowstart[i + 1] = incl[i] + bsum[blockIdx.x];
        int d = cnt[i];
        dinv[i] = (d > 0) ? rsqrtf((float)d) : 0.0f;
    }
    if (i == 0) rowstart[0] = 0;
}

__global__ void fill_csr(const int* __restrict__ row, const int* __restrict__ col,
                         const int* __restrict__ rowstart, const unsigned short* __restrict__ pos,
                         int* __restrict__ srcidx, int E) {
    int e = blockIdx.x * blockDim.x + threadIdx.x;
    if (e < E) srcidx[rowstart[col[e]] + (int)pos[e]] = row[e];
}

__global__ void pad_csr(const int* __restrict__ rowstart, const int* __restrict__ cnt,
                        int* __restrict__ srcidx, int N) {
    int i = blockIdx.x * blockDim.x + threadIdx.x;
    if (i >= N) return;
    int b = rowstart[i] + cnt[i], en = rowstart[i + 1];
    for (int e = b; e < en; ++e) srcidx[e] = N;
}

// ==================== t0 GEMM layer1 (per-k): xh @ [Wa | Wb] -> outH (scaled by dinv) + pre ====================
template<int CT, int CTA, int CH>
__global__ __launch_bounds__(256, 4)
void gemm_t0(const ushort_t* __restrict__ s2, int s2s, const short* __restrict__ fragbuf,
             const float* __restrict__ biasB, const float* __restrict__ dinv,
             int FB, int N, uint_t* __restrict__ pre, uint_t* __restrict__ outH) {
    constexpr int PP = (CT - CTA) * 8;
    constexpr int PA = CTA * 8;
    const int k = blockIdx.y;
    const int n0 = blockIdx.x * 128;
    const int t = threadIdx.x;
    const int w = t >> 6, lane = t & 63, quad = lane >> 4, lr = lane & 15;
    const short* fb = fragbuf + (size_t)k * CH * CT * 512;

    int r0 = n0 + w * 32 + lr;
    int m0 = r0 < N ? r0 : N - 1;
    int m1 = (r0 + 16) < N ? (r0 + 16) : N - 1;

    bf16x8 a0v[CH], a1v[CH];
#pragma unroll
    for (int c = 0; c < CH; ++c) {
        int off = c * 32 + quad * 8;
        a0v[c] = *(const bf16x8*)&s2[(size_t)m0 * s2s + off];
        a1v[c] = *(const bf16x8*)&s2[(size_t)m1 * s2s + off];
    }

    __shared__ short lds_b[CH * CT * 512];
    {
        constexpr int CHUNKS = CH * CT * 64;
#pragma unroll
        for (int i = 0; i < (CHUNKS + 255) / 256; ++i) {
            int idx = i * 256 + t;
            if (CHUNKS % 256 == 0 || idx < CHUNKS)
                *(bf16x8*)&lds_b[idx * 8] = *(const bf16x8*)&fb[(size_t)idx * 8];
        }
    }
    __syncthreads();

    f32x4 acc[2][CT];
#pragma unroll
    for (int rt = 0; rt < 2; ++rt)
#pragma unroll
        for (int ct = 0; ct < CT; ++ct) acc[rt][ct] = (f32x4){0.f, 0.f, 0.f, 0.f};

#pragma unroll
    for (int c = 0; c < CH; ++c) {
#pragma unroll
        for (int ct = 0; ct < CT; ++ct) {
            bf16x8 bfr = *(const bf16x8*)&lds_b[((size_t)c * CT + ct) * 512 + lane * 8];
            acc[0][ct] = __builtin_amdgcn_mfma_f32_16x16x32_bf16(a0v[c], bfr, acc[0][ct], 0, 0, 0);
            acc[1][ct] = __builtin_amdgcn_mfma_f32_16x16x32_bf16(a1v[c], bfr, acc[1][ct], 0, 0, 0);
        }
    }

#pragma unroll
    for (int rt = 0; rt < 2; ++rt) {
#pragma unroll
        for (int i = 0; i < 4; ++i) {
            int n = n0 + w * 32 + rt * 16 + quad * 4 + i;
            if (n >= N) continue;
            float dnv = dinv[n];
#pragma unroll
            for (int ct = 0; ct < CT; ++ct) {
                int col = ct * 16 + lr;
                float v = acc[rt][ct][i];
                if (ct < CTA) {
                    v *= dnv;                       // pre-scale msg by dinv[src]
                } else {
                    int c2 = col - CTA * 16;
                    if (c2 < FB) v += biasB[(size_t)k * FB + c2];
                }
                float vn = __shfl_xor(v, 1);
                uint_t p = pack2(v, vn);
                uint_t p2 = __shfl_xor(p, 2);
                if (!(lr & 3)) {
                    if (ct < CTA) {
                        *(uint2*)&outH[((size_t)n * 2 + k) * PA + (col >> 1)] = make_uint2(p, p2);
                    } else {
                        int c2 = col - CTA * 16;
                        *(uint2*)&pre[((size_t)n * 2 + k) * PP + (c2 >> 1)] = make_uint2(p, p2);
                    }
                }
            }
        }
    }
}

// ==================== fused mid GEMM: t1-L1 (relu+mean -> hh) then t0-L2 in one block ====================
// Phase 1 = gemm_t1_l1 body; hh tile kept in LDS (re-using dead B1 space) feeds phase 2
// (= gemm_t0<6,3,2> for both k). Eliminates hh global re-read + one kernel launch.
// Phase-2 output MUST NOT alias s1 (other blocks still read it) -> writes outH2 (b16B) + pre.
__global__ __launch_bounds__(256)
void gemm_mid(const ushort_t* __restrict__ s1, const ushort_t* __restrict__ xh,
              const short* __restrict__ fragB1, const short* __restrict__ fragB2,
              const float* __restrict__ bias1, const float* __restrict__ bias2,
              const float* __restrict__ dinv, int N,
              uint_t* __restrict__ hhU, uint_t* __restrict__ pre, uint_t* __restrict__ outH2) {
    constexpr int CT1 = 4, CH1 = 6;        // phase 1: K=64(agg,2chunks)+128(x,4chunks) -> 64
    constexpr int CT2 = 6, CTA2 = 3, CH2 = 2;  // phase 2: hh(64) -> [41pad48 | 41pad48]
    const int n0 = blockIdx.x * 128;
    const int t = threadIdx.x;
    const int w = t >> 6, lane = t & 63, quad = lane >> 4, lr = lane & 15;

    __shared__ short lds[2 * CH1 * CT1 * 512];   // 48 KB; after phase 1: [0,8192)=hh tile, [8192,20480)=B2

    int r0 = n0 + w * 32 + lr;
    int m0 = r0 < N ? r0 : N - 1;
    int m1 = (r0 + 16) < N ? (r0 + 16) : N - 1;

    // hoisted phase-1 A loads
    bf16x8 s0a[2][2], s1a[2][2];   // [c][k]
    bf16x8 x0a[4], x1a[4];
#pragma unroll
    for (int c = 0; c < 2; ++c) {
        int off = c * 32 + quad * 8;
#pragma unroll
        for (int kk = 0; kk < 2; ++kk) {
            s0a[c][kk] = *(const bf16x8*)&s1[((size_t)m0 * 2 + kk) * 64 + off];
            s1a[c][kk] = *(const bf16x8*)&s1[((size_t)m1 * 2 + kk) * 64 + off];
        }
    }
#pragma unroll
    for (int c = 0; c < 4; ++c) {
        int off = c * 32 + quad * 8;
        x0a[c] = *(const bf16x8*)&xh[(size_t)m0 * 128 + off];
        x1a[c] = *(const bf16x8*)&xh[(size_t)m1 * 128 + off];
    }

    // stage B1 (48 KB, both k)
    {
        constexpr int CHUNKS = 2 * CH1 * CT1 * 64;
#pragma unroll
        for (int i = 0; i < CHUNKS / 256; ++i) {
            int idx = i * 256 + t;
            *(bf16x8*)&lds[idx * 8] = *(const bf16x8*)&fragB1[(size_t)idx * 8];
        }
    }
    __syncthreads();

    f32x4 acc[2][2][CT1];
#pragma unroll
    for (int k = 0; k < 2; ++k)
#pragma unroll
        for (int rt = 0; rt < 2; ++rt)
#pragma unroll
            for (int ct = 0; ct < CT1; ++ct) acc[k][rt][ct] = (f32x4){0.f, 0.f, 0.f, 0.f};

#pragma unroll
    for (int c = 0; c < CH1; ++c) {
#pragma unroll
        for (int k = 0; k < 2; ++k) {
            bf16x8 a0 = (c < 2) ? s0a[c][k] : x0a[c - 2];
            bf16x8 a1 = (c < 2) ? s1a[c][k] : x1a[c - 2];
#pragma unroll
            for (int ct = 0; ct < CT1; ++ct) {
                bf16x8 b = *(const bf16x8*)&lds[(((size_t)k * CH1 + c) * CT1 + ct) * 512 + lane * 8];
                acc[k][0][ct] = __builtin_amdgcn_mfma_f32_16x16x32_bf16(a0, b, acc[k][0][ct], 0, 0, 0);
                acc[k][1][ct] = __builtin_amdgcn_mfma_f32_16x16x32_bf16(a1, b, acc[k][1][ct], 0, 0, 0);
            }
        }
    }
    __syncthreads();   // all B1 LDS reads complete; space re-usable

    short* lds_h = lds;           // 128 x 64 bf16 tile (8192 shorts)
    short* ldsB2 = lds + 8192;    // 12288 shorts = both-k B2 frags

    // phase-1 epilogue: hh -> global + LDS tile
#pragma unroll
    for (int rt = 0; rt < 2; ++rt) {
#pragma unroll
        for (int i = 0; i < 4; ++i) {
            int n = n0 + w * 32 + rt * 16 + quad * 4 + i;
            if (n >= N) continue;
#pragma unroll
            for (int ct = 0; ct < CT1; ++ct) {
                int col = ct * 16 + lr;
                float v0 = fmaxf(acc[0][rt][ct][i] + bias1[col], 0.0f);
                float v1 = fmaxf(acc[1][rt][ct][i] + bias1[64 + col], 0.0f);
                float m = 0.5f * (v0 + v1);
                float mn = __shfl_xor(m, 1);
                uint_t p = pack2(m, mn);
                uint_t p2 = __shfl_xor(p, 2);
                if (!(lr & 3)) {
                    *(uint2*)&hhU[(size_t)n * 32 + (col >> 1)] = make_uint2(p, p2);
                    *(uint2*)&lds_h[(size_t)(n - n0) * 64 + col] = make_uint2(p, p2);
                }
            }
        }
    }

    // stage B2 (24 KB, both k) into re-used LDS
    {
        constexpr int CHUNKS2 = 2 * CH2 * CT2 * 64;   // 1536 chunks
#pragma unroll
        for (int i = 0; i < CHUNKS2 / 256; ++i) {
            int idx = i * 256 + t;
            *(bf16x8*)&ldsB2[idx * 8] = *(const bf16x8*)&fragB2[(size_t)idx * 8];
        }
    }
    __syncthreads();

    // phase 2: A = hh tile from LDS (rows local, clamped rows stay in-block)
    int l0 = m0 - n0, l1 = m1 - n0;
    bf16x8 a20[CH2], a21[CH2];
#pragma unroll
    for (int c = 0; c < CH2; ++c) {
        int off = c * 32 + quad * 8;
        a20[c] = *(const bf16x8*)&lds_h[(size_t)l0 * 64 + off];
        a21[c] = *(const bf16x8*)&lds_h[(size_t)l1 * 64 + off];
    }

    f32x4 acc2[2][2][CT2];
#pragma unroll
    for (int k = 0; k < 2; ++k)
#pragma unroll
        for (int rt = 0; rt < 2; ++rt)
#pragma unroll
            for (int ct = 0; ct < CT2; ++ct) acc2[k][rt][ct] = (f32x4){0.f, 0.f, 0.f, 0.f};

#pragma unroll
    for (int c = 0; c < CH2; ++c) {
#pragma unroll
        for (int k = 0; k < 2; ++k) {
#pragma unroll
            for (int ct = 0; ct < CT2; ++ct) {
                bf16x8 b = *(const bf16x8*)&ldsB2[(((size_t)k * CH2 + c) * CT2 + ct) * 512 + lane * 8];
                acc2[k][0][ct] = __builtin_amdgcn_mfma_f32_16x16x32_bf16(a20[c], b, acc2[k][0][ct], 0, 0, 0);
                acc2[k][1][ct] = __builtin_amdgcn_mfma_f32_16x16x32_bf16(a21[c], b, acc2[k][1][ct], 0, 0, 0);
            }
        }
    }

    // phase-2 epilogue (gemm_t0<6,3,2> style, both k), width-48 layouts
#pragma unroll
    for (int k = 0; k < 2; ++k) {
#pragma unroll
        for (int rt = 0; rt < 2; ++rt) {
#pragma unroll
            for (int i = 0; i < 4; ++i) {
                int n = n0 + w * 32 + rt * 16 + quad * 4 + i;
                if (n >= N) continue;
                float dnv = dinv[n];
#pragma unroll
                for (int ct = 0; ct < CT2; ++ct) {
                    int col = ct * 16 + lr;
                    float v = acc2[k][rt][ct][i];
                    if (ct < CTA2) {
                        v *= dnv;
                    } else {
                        int c2 = col - CTA2 * 16;
                        if (c2 < 41) v += bias2[(size_t)k * 41 + c2];
                    }
                    float vn = __shfl_xor(v, 1);
                    uint_t p = pack2(v, vn);
                    uint_t p2 = __shfl_xor(p, 2);
                    if (!(lr & 3)) {
                        if (ct < CTA2) {
                            *(uint2*)&outH2[((size_t)n * 2 + k) * 24 + (col >> 1)] = make_uint2(p, p2);
                        } else {
                            int c2 = col - CTA2 * 16;
                            *(uint2*)&pre[((size_t)n * 2 + k) * 24 + (c2 >> 1)] = make_uint2(p, p2);
                        }
                    }
                }
            }
        }
    }
}

// ===== t1 GEMM layer2: relu+mean+log_softmax -> d_out f32 =====
__global__ __launch_bounds__(256, 3)
void gemm_t1_l2(const ushort_t* __restrict__ s1, const ushort_t* __restrict__ hh,
                const short* __restrict__ fragbuf, const float* __restrict__ bias,
                int N, float* __restrict__ out) {
    constexpr int CT = 3, CH = 4;
    const int n0 = blockIdx.x * 128;
    const int t = threadIdx.x;
    const int w = t >> 6, lane = t & 63, quad = lane >> 4, lr = lane & 15;

    int r0 = n0 + w * 32 + lr;
    int m0 = r0 < N ? r0 : N - 1;
    int m1 = (r0 + 16) < N ? (r0 + 16) : N - 1;

    bf16x8 s0a[2][2], s1a[2][2];   // [c][k]
    bf16x8 h0a[2], h1a[2];
#pragma unroll
    for (int c = 0; c < 2; ++c) {
        int off = c * 32 + quad * 8;
#pragma unroll
        for (int kk = 0; kk < 2; ++kk) {
            s0a[c][kk] = *(const bf16x8*)&s1[((size_t)m0 * 2 + kk) * 48 + off];
            s1a[c][kk] = *(const bf16x8*)&s1[((size_t)m1 * 2 + kk) * 48 + off];
        }
    }
#pragma unroll
    for (int c = 0; c < 2; ++c) {
        int off = c * 32 + quad * 8;
        h0a[c] = *(const bf16x8*)&hh[(size_t)m0 * 64 + off];
        h1a[c] = *(const bf16x8*)&hh[(size_t)m1 * 64 + off];
    }

    __shared__ short lds_b[2 * CH * CT * 512];   // 24 KB, both k
    {
        constexpr int CHUNKS = 2 * CH * CT * 64;
#pragma unroll
        for (int i = 0; i < CHUNKS / 256; ++i) {
            int idx = i * 256 + t;
            *(bf16x8*)&lds_b[idx * 8] = *(const bf16x8*)&fragbuf[(size_t)idx * 8];
        }
    }
    __syncthreads();

    f32x4 acc[2][2][CT];
#pragma unroll
    for (int k = 0; k < 2; ++k)
#pragma unroll
        for (int rt = 0; rt < 2; ++rt)
#pragma unroll
            for (int ct = 0; ct < CT; ++ct) acc[k][rt][ct] = (f32x4){0.f, 0.f, 0.f, 0.f};

#pragma unroll
    for (int c = 0; c < CH; ++c) {
#pragma unroll
        for (int k = 0; k < 2; ++k) {
            bf16x8 a0 = (c < 2) ? s0a[c][k] : h0a[c - 2];
            bf16x8 a1 = (c < 2) ? s1a[c][k] : h1a[c - 2];
#pragma unroll
            for (int ct = 0; ct < CT; ++ct) {
                bf16x8 b = *(const bf16x8*)&lds_b[(((size_t)k * CH + c) * CT + ct) * 512 + lane * 8];
                acc[k][0][ct] = __builtin_amdgcn_mfma_f32_16x16x32_bf16(a0, b, acc[k][0][ct], 0, 0, 0);
                acc[k][1][ct] = __builtin_amdgcn_mfma_f32_16x16x32_bf16(a1, b, acc[k][1][ct], 0, 0, 0);
            }
        }
    }

#pragma unroll
    for (int rt = 0; rt < 2; ++rt) {
#pragma unroll
        for (int i = 0; i < 4; ++i) {
            int n = n0 + w * 32 + rt * 16 + quad * 4 + i;
            float m[CT];
            float mx = -1e30f;
#pragma unroll
            for (int ct = 0; ct < CT; ++ct) {
                int col = ct * 16 + lr;
                float b0 = (col < 41) ? bias[col] : 0.0f;
                float b1v = (col < 41) ? bias[41 + col] : 0.0f;
                float v0 = fmaxf(acc[0][rt][ct][i] + b0, 0.0f);
                float v1 = fmaxf(acc[1][rt][ct][i] + b1v, 0.0f);
                m[ct] = 0.5f * (v0 + v1);
                if (col < 41) mx = fmaxf(mx, m[ct]);
            }
#pragma unroll
            for (int msk = 1; msk < 16; msk <<= 1) mx = fmaxf(mx, __shfl_xor(mx, msk));
            float s = 0.0f;
#pragma unroll
            for (int ct = 0; ct < CT; ++ct) {
                int col = ct * 16 + lr;
                if (col < 41) s += __expf(m[ct] - mx);
            }
#pragma unroll
            for (int msk = 1; msk < 16; msk <<= 1) s += __shfl_xor(s, msk);
            float ls = __logf(s);
            if (n < N) {
#pragma unroll
                for (int ct = 0; ct < CT; ++ct) {
                    int col = ct * 16 + lr;
                    if (col < 41) out[(size_t)n * 41 + col] = m[ct] - mx - ls;
                }
            }
        }
    }
}

// ==================== CSR gather, width 64: wave = full row (scalarized bounds) ====================
template<bool SCALE_OUT>
__global__ __launch_bounds__(256)
void gather32(const int* __restrict__ rowstart, const int* __restrict__ srcidx,
              const float* __restrict__ dinv, const uint_t* __restrict__ msg,
              const uint_t* __restrict__ pre, uint_t* __restrict__ outH, int N) {
    int gt = blockIdx.x * 256 + threadIdx.x;
    int n = gt >> 6;
    if (n >= N) return;
    const uint_t lo = (uint_t)(gt & 63);          // k*32+pair
    const int STR = 64;
    // n is wave-uniform (256-thread blocks, 64-lane waves): force bounds to SGPRs.
    int beg = __builtin_amdgcn_readfirstlane(rowstart[n]);
    int end = __builtin_amdgcn_readfirstlane(rowstart[n + 1]);
    float dn = __uint_as_float(__builtin_amdgcn_readfirstlane(__float_as_uint(dinv[n])));
    size_t o = (size_t)n * STR + lo;
    uint_t p = 0;
    if (pre) p = pre[o];

    float ax0 = 0.f, ax1 = 0.f, ay0 = 0.f, ay1 = 0.f;
    int e = beg;
    for (; e + 8 <= end; e += 8) {
        int4 sa = *(const int4*)&srcidx[e];
        int4 sb = *(const int4*)&srcidx[e + 4];
        uint_t m0 = msg[(uint_t)(sa.x * STR) + lo];
        uint_t m1 = msg[(uint_t)(sa.y * STR) + lo];
        uint_t m2 = msg[(uint_t)(sa.z * STR) + lo];
        uint_t m3 = msg[(uint_t)(sa.w * STR) + lo];
        uint_t m4 = msg[(uint_t)(sb.x * STR) + lo];
        uint_t m5 = msg[(uint_t)(sb.y * STR) + lo];
        uint_t m6 = msg[(uint_t)(sb.z * STR) + lo];
        uint_t m7 = msg[(uint_t)(sb.w * STR) + lo];
        ax0 += __uint_as_float(m0 << 16); ay0 += __uint_as_float(m0 & 0xffff0000u);
        ax1 += __uint_as_float(m1 << 16); ay1 += __uint_as_float(m1 & 0xffff0000u);
        ax0 += __uint_as_float(m2 << 16); ay0 += __uint_as_float(m2 & 0xffff0000u);
        ax1 += __uint_as_float(m3 << 16); ay1 += __uint_as_float(m3 & 0xffff0000u);
        ax0 += __uint_as_float(m4 << 16); ay0 += __uint_as_float(m4 & 0xffff0000u);
        ax1 += __uint_as_float(m5 << 16); ay1 += __uint_as_float(m5 & 0xffff0000u);
        ax0 += __uint_as_float(m6 << 16); ay0 += __uint_as_float(m6 & 0xffff0000u);
        ax1 += __uint_as_float(m7 << 16); ay1 += __uint_as_float(m7 & 0xffff0000u);
    }
    if (e < end) {   // one 4-batch remains (rows padded to multiple of 4)
        int4 sa = *(const int4*)&srcidx[e];
        uint_t m0 = msg[(uint_t)(sa.x * STR) + lo];
        uint_t m1 = msg[(uint_t)(sa.y * STR) + lo];
        uint_t m2 = msg[(uint_t)(sa.z * STR) + lo];
        uint_t m3 = msg[(uint_t)(sa.w * STR) + lo];
        ax0 += __uint_as_float(m0 << 16); ay0 += __uint_as_float(m0 & 0xffff0000u);
        ax1 += __uint_as_float(m1 << 16); ay1 += __uint_as_float(m1 & 0xffff0000u);
        ax0 += __uint_as_float(m2 << 16); ay0 += __uint_as_float(m2 & 0xffff0000u);
        ax1 += __uint_as_float(m3 << 16); ay1 += __uint_as_float(m3 & 0xffff0000u);
    }
    float ax = (ax0 + ax1) * dn;
    float ay = (ay0 + ay1) * dn;
    if (pre) {
        ax = fmaxf(ax + bf2f((ushort_t)p), 0.0f);
        ay = fmaxf(ay + bf2f((ushort_t)(p >> 16)), 0.0f);
    }
    if (SCALE_OUT) { ax *= dn; ay *= dn; }
    outH[o] = pack2(ax, ay);
}

// ==================== CSR gather, row width 48: all 64 lanes active (n = gt/48) ====================
template<bool SCALE_OUT>
__global__ __launch_bounds__(256)
void gather24(const int* __restrict__ rowstart, const int* __restrict__ srcidx,
              const float* __restrict__ dinv, const uint_t* __restrict__ msg,
              const uint_t* __restrict__ pre, uint_t* __restrict__ outH, int N) {
    int gt = blockIdx.x * 256 + threadIdx.x;
    int n = gt / 48;
    if (n >= N) return;
    const uint_t lo = (uint_t)(gt - n * 48);      // k*24+pair in [0,48)
    const int STR = 48;
    int beg = rowstart[n], end = rowstart[n + 1];
    float dn = dinv[n];
    size_t o = (size_t)n * STR + lo;
    uint_t p = 0;
    if (pre) p = pre[o];

    float ax0 = 0.f, ax1 = 0.f, ay0 = 0.f, ay1 = 0.f;
    int e = beg;
    for (; e + 8 <= end; e += 8) {
        int4 sa = *(const int4*)&srcidx[e];
        int4 sb = *(const int4*)&srcidx[e + 4];
        uint_t m0 = msg[(uint_t)(sa.x * STR) + lo];
        uint_t m1 = msg[(uint_t)(sa.y * STR) + lo];
        uint_t m2 = msg[(uint_t)(sa.z * STR) + lo];
        uint_t m3 = msg[(uint_t)(sa.w * STR) + lo];
        uint_t m4 = msg[(uint_t)(sb.x * STR) + lo];
        uint_t m5 = msg[(uint_t)(sb.y * STR) + lo];
        uint_t m6 = msg[(uint_t)(sb.z * STR) + lo];
        uint_t m7 = msg[(uint_t)(sb.w * STR) + lo];
        ax0 += __uint_as_float(m0 << 16); ay0 += __uint_as_float(m0 & 0xffff0000u);
        ax1 += __uint_as_float(m1 << 16); ay1 += __uint_as_float(m1 & 0xffff0000u);
        ax0 += __uint_as_float(m2 << 16); ay0 += __uint_as_float(m2 & 0xffff0000u);
        ax1 += __uint_as_float(m3 << 16); ay1 += __uint_as_float(m3 & 0xffff0000u);
        ax0 += __uint_as_float(m4 << 16); ay0 += __uint_as_float(m4 & 0xffff0000u);
        ax1 += __uint_as_float(m5 << 16); ay1 += __uint_as_float(m5 & 0xffff0000u);
        ax0 += __uint_as_float(m6 << 16); ay0 += __uint_as_float(m6 & 0xffff0000u);
        ax1 += __uint_as_float(m7 << 16); ay1 += __uint_as_float(m7 & 0xffff0000u);
    }
    if (e < end) {
        int4 sa = *(const int4*)&srcidx[e];
        uint_t m0 = msg[(uint_t)(sa.x * STR) + lo];
        uint_t m1 = msg[(uint_t)(sa.y * STR) + lo];
        uint_t m2 = msg[(uint_t)(sa.z * STR) + lo];
        uint_t m3 = msg[(uint_t)(sa.w * STR) + lo];
        ax0 += __uint_as_float(m0 << 16); ay0 += __uint_as_float(m0 & 0xffff0000u);
        ax1 += __uint_as_float(m1 << 16); ay1 += __uint_as_float(m1 & 0xffff0000u);
        ax0 += __uint_as_float(m2 << 16); ay0 += __uint_as_float(m2 & 0xffff0000u);
        ax1 += __uint_as_float(m3 << 16); ay1 += __uint_as_float(m3 & 0xffff0000u);
    }
    float ax = (ax0 + ax1) * dn;
    float ay = (ay0 + ay1) * dn;
    if (pre) {
        ax = fmaxf(ax + bf2f((ushort_t)p), 0.0f);
        ay = fmaxf(ay + bf2f((ushort_t)(p >> 16)), 0.0f);
    }
    if (SCALE_OUT) { ax *= dn; ay *= dn; }
    outH[o] = pack2(ax, ay);
}

extern "C" void kernel_launch(void* const* d_in, const int* in_sizes, int n_in,
                              void* d_out, int out_size, void* d_ws, size_t ws_size,
                              hipStream_t stream) {
    const float* x       = (const float*)d_in[0];
    const int*   ei      = (const int*)  d_in[1];
    const float* w1_init = (const float*)d_in[2];
    const float* w1      = (const float*)d_in[3];
    const float* w1_root = (const float*)d_in[4];
    const float* b1      = (const float*)d_in[5];
    const float* w2_init = (const float*)d_in[6];
    const float* w2      = (const float*)d_in[7];
    const float* w2_root = (const float*)d_in[8];
    const float* b2      = (const float*)d_in[9];

    const int Fin1 = 128;
    int N = in_sizes[0] / Fin1;          // 100000
    int E = in_sizes[1] / 2;             // 1600000
    const int* row = ei;
    const int* col = ei + E;

    char* ws = (char*)d_ws;
    size_t off = 0;
    auto carve = [&](size_t bytes) -> void* {
        void* p = ws + off;
        off += (bytes + 255) & ~(size_t)255;
        return p;
    };
    int nblkN = (N + TPB - 1) / TPB;   // 391 (<=512 for one-block scan)
    int*      cnt      = (int*)     carve((size_t)N * 4);
    int*      incl     = (int*)     carve((size_t)N * 4);
    int*      rowstart = (int*)     carve((size_t)(N + 1) * 4);
    int*      bsum     = (int*)     carve((size_t)nblkN * 4);
    float*    dinv     = (float*)   carve((size_t)N * 4);
    unsigned short* pos = (unsigned short*)carve((size_t)E * 2);      // rank fits in u16
    int*      srcidx   = (int*)     carve((size_t)(E + 3 * (size_t)N + 64) * 4);  // padded CSR
    short*    swz      = (short*)   carve((size_t)(SWZ_A + SWZ_B + SWZ_C + SWZ_D) * 2);
    ushort_t* xh       = (ushort_t*)carve((size_t)N * 128 * 2);          // bf16 x
    ushort_t* hh       = (ushort_t*)carve((size_t)N * 64 * 2);           // bf16 h
    ushort_t* b16A     = (ushort_t*)carve((size_t)N * 2 * 64 * 2 + 256); // P / agg (+sentinel row)
    ushort_t* b16B     = (ushort_t*)carve((size_t)N * 2 * 64 * 2 + 256); // out_t   (+sentinel row)
    uint_t*   pre      = (uint_t*)  carve((size_t)N * 2 * 32 * 4);       // packed bf16 pre

    // ---- sentinel msg rows (width-64 layout) + cnt zeroed ----
    hipMemsetAsync((char*)b16A + (size_t)N * 256, 0, 256, stream);
    hipMemsetAsync((char*)b16B + (size_t)N * 256, 0, 256, stream);
    hipMemsetAsync(cnt, 0, (size_t)N * 4, stream);

    // ---- fused preamble: rank || weight swizzle || x->bf16 ----
    int nEb = (E + TPB - 1) / TPB;                         // 6250
    int swztot = SWZ_A + SWZ_B + SWZ_C + SWZ_D;
    int nSb = (swztot + TPB - 1) / TPB;                    // 320
    int n4 = N * 128 / 4;
    int nCb = (n4 + TPB - 1) / TPB;                        // 12500
    pre1<<<nEb + nSb + nCb, TPB, 0, stream>>>(col, cnt, pos, E, nEb,
                                              w1_init, w1, w1_root, w2_init, w2, w2_root,
                                              swz, nSb, (const float4*)x, (uint2*)xh, n4);

    // ---- scan chain + CSR fill ----
    scan_block  <<<nblkN, TPB, 0, stream>>>(cnt, incl, bsum, N);
    scan_bsums  <<<1, 512, 0, stream>>>(bsum, nblkN);
    finalize_csr<<<nblkN, TPB, 0, stream>>>(incl, bsum, cnt, rowstart, dinv, N);
    pad_csr     <<<nblkN, TPB, 0, stream>>>(rowstart, cnt, srcidx, N);
    fill_csr    <<<(E + TPB - 1) / TPB, TPB, 0, stream>>>(row, col, rowstart, pos, srcidx, E);

    const short* swzA = swz;
    const short* swzB = swz + SWZ_A;
    const short* swzC = swz + SWZ_A + SWZ_B;
    const short* swzD = swz + SWZ_A + SWZ_B + SWZ_C;
    dim3 gg2((N + 127) / 128, 2);
    dim3 gg1((N + 127) / 128, 1);
    int g32 = (N * 64 + TPB - 1) / TPB;                     // 25000
    int g24 = (N * 48 + TPB - 1) / TPB;                     // 18750

    // ---- layer 1 (128 -> 64) ----
    gemm_t0<8, 4, 4><<<gg2, TPB, 0, stream>>>(xh, 128, swzA, b1, dinv, 64, N, pre, (uint_t*)b16A);
    gather32<true ><<<g32, TPB, 0, stream>>>(rowstart, srcidx, dinv, (const uint_t*)b16A,
                                             pre, (uint_t*)b16B, N);
    gather32<false><<<g32, TPB, 0, stream>>>(rowstart, srcidx, dinv, (const uint_t*)b16B,
                                             nullptr, (uint_t*)b16A, N);

    // ---- fused t1-L1 + t0-L2: reads b16A(w64)+xh, writes hh + b16B(w48) + pre(w48) ----
    gemm_mid<<<gg1, TPB, 0, stream>>>(b16A, xh, swzB, swzC, b1 + 2 * 64, b2, dinv, N,
                                      (uint_t*)hh, pre, (uint_t*)b16B);

    // ---- sentinel rows for width-48 layout (after all width-64 consumers) ----
    hipMemsetAsync((char*)b16A + (size_t)N * 192, 0, 192, stream);
    hipMemsetAsync((char*)b16B + (size_t)N * 192, 0, 192, stream);

    // ---- layer 2 gathers: b16B -> b16A -> b16B ----
    gather24<true ><<<g24, TPB, 0, stream>>>(rowstart, srcidx, dinv, (const uint_t*)b16B,
                                             pre, (uint_t*)b16A, N);
    gather24<false><<<g24, TPB, 0, stream>>>(rowstart, srcidx, dinv, (const uint_t*)b16A,
                                             nullptr, (uint_t*)b16B, N);
    gemm_t1_l2<<<gg1, TPB, 0, stream>>>(b16B, hh, swzD, b2 + 2 * 41, N, (float*)d_out);
}